// Round 7
// baseline (1306.617 us; speedup 1.0000x reference)
//
#include <hip/hip_runtime.h>
#include <cmath>

// ---------------------------------------------------------------------------
// Hetero-SAGE GNN (4 layers, 10 relations, D=128) + edge classifier.
// R7: (a) XCD-ranged CSR build: hist & scatter run 8 dst-range passes keyed
//     by blockIdx.x&7 (round-robin XCD mapping) so esrc/counts cache lines
//     are XCD-private -> kills the 13x partial-line write amplification.
//     (b) agg kernels: 16 lanes x f16x8 (16B/lane) per row, 16 rows/block.
// Carried: f16 gather tables, in-place x, layer-3 pruning, MFMA f16x3 GEMMs.
// ---------------------------------------------------------------------------

typedef _Float16 f16x8 __attribute__((ext_vector_type(8)));
typedef _Float16 f16x4 __attribute__((ext_vector_type(4)));
typedef float f32x4 __attribute__((ext_vector_type(4)));

#define NREL 10
#define NCOUNTS 546000
#define NEDGES  2300000
#define NVISIT  100000
#define PLW 546816
#define WT_ELEMS (4 * PLW + 67584)

struct RelMeta { const int* ei[NREL]; int E[NREL]; int cbc[NREL]; float scl[NREL]; };
struct GatherMeta { const float* emb[6]; const int* nid[6]; int rows[6]; int off[6]; };
struct AggMeta { const int* rp[5]; float* mean[5]; int M[5]; };
struct VAggMeta { const int* rp[5]; const _Float16* Y[5]; };
struct MTask {
  const float* A0; const float* A1;   // A1 = rows for k in [128,256)
  const _Float16* W;                  // [2][128][Kpad] h-plane then l-plane
  const float* bias;                  // nullable
  float* out;                         // nullable (fp32 output)
  _Float16* out16;                    // nullable (f16 output)
  int M, blkOff, K, relu;
};
struct MMeta { MTask t[6]; int nTasks; };

// ---------------- init gather (visit also emits f16 copy) ------------------
__global__ __launch_bounds__(256) void gather_all(GatherMeta g, float* __restrict__ x,
                                                  _Float16* __restrict__ xv16) {
  int t = blockIdx.y;
  int i = blockIdx.x * 256 + threadIdx.x;
  if (i >= g.rows[t] * 32) return;
  int row = i >> 5, q = i & 31;
  int s = g.nid[t][row];
  float4 v = *(const float4*)(g.emb[t] + (size_t)s * 128 + q * 4);
  *(float4*)(x + (size_t)(g.off[t] + row) * 128 + q * 4) = v;
  if (t == 1) {
    f16x4 h;
    h[0] = (_Float16)v.x; h[1] = (_Float16)v.y;
    h[2] = (_Float16)v.z; h[3] = (_Float16)v.w;
    *(f16x4*)(xv16 + (size_t)row * 128 + q * 4) = h;
  }
}

// ---------------- CSR build: XCD-ranged hist + scatter ---------------------
// blockIdx.x&7 = dst-range (consecutive blocks round-robin XCDs -> each
// range's counts/esrc lines stay XCD-private; full lines before eviction).
__global__ __launch_bounds__(256) void hist_ranged(RelMeta m, int* __restrict__ counts) {
  int r = blockIdx.y;
  int bx = blockIdx.x;
  int rng = bx & 7;
  int e = (bx >> 3) * 256 + threadIdx.x;
  if (e >= m.E[r]) return;
  int c = m.ei[r][m.E[r] + e];
  int rr = (int)((float)c * m.scl[r]); if (rr > 7) rr = 7;
  if (rr != rng) return;
  atomicAdd(&counts[m.cbc[r] + c], 1);
}

__global__ __launch_bounds__(1024) void scan1(const int* __restrict__ counts,
                                              int* __restrict__ partials) {
  __shared__ int s[1024];
  int i = blockIdx.x * 1024 + threadIdx.x;
  s[threadIdx.x] = (i < NCOUNTS) ? counts[i] : 0;
  __syncthreads();
  for (int off = 512; off > 0; off >>= 1) {
    if (threadIdx.x < off) s[threadIdx.x] += s[threadIdx.x + off];
    __syncthreads();
  }
  if (threadIdx.x == 0) partials[blockIdx.x] = s[0];
}

__global__ __launch_bounds__(1024) void scan2(int* __restrict__ partials, int nb) {
  __shared__ int s[1024];
  int t = threadIdx.x;
  int v = (t < nb) ? partials[t] : 0;
  s[t] = v;
  __syncthreads();
  for (int off = 1; off < 1024; off <<= 1) {
    int add = (t >= off) ? s[t - off] : 0;
    __syncthreads();
    s[t] += add;
    __syncthreads();
  }
  if (t < nb) partials[t] = s[t] - v;  // exclusive
}

__global__ __launch_bounds__(1024) void scan3(int* __restrict__ counts,
                                              int* __restrict__ prefix,
                                              const int* __restrict__ partials) {
  __shared__ int s[1024];
  int t = threadIdx.x;
  int i = blockIdx.x * 1024 + t;
  int v = (i < NCOUNTS) ? counts[i] : 0;
  s[t] = v;
  __syncthreads();
  for (int off = 1; off < 1024; off <<= 1) {
    int add = (t >= off) ? s[t - off] : 0;
    __syncthreads();
    s[t] += add;
    __syncthreads();
  }
  int P = partials[blockIdx.x] + s[t] - v;
  if (i < NCOUNTS) { prefix[i] = P; counts[i] = P; /* cursor */ }
  if (blockIdx.x == 0 && t == 0) prefix[NCOUNTS] = NEDGES;
}

__global__ __launch_bounds__(256) void scatter_ranged(RelMeta m, int* __restrict__ cursor,
                                                      int* __restrict__ esrc) {
  int r = blockIdx.y;
  int bx = blockIdx.x;
  int rng = bx & 7;
  int e = (bx >> 3) * 256 + threadIdx.x;
  if (e >= m.E[r]) return;
  const int* ei = m.ei[r];
  int c = ei[m.E[r] + e];
  int rr = (int)((float)c * m.scl[r]); if (rr > 7) rr = 7;
  if (rr != rng) return;
  int pos = atomicAdd(&cursor[m.cbc[r] + c], 1);
  esrc[pos] = ei[e];
}

// ---------------- weight split/transpose prep ------------------------------
__global__ __launch_bounds__(256) void prep_split(
    const float* __restrict__ W_l, const float* __restrict__ b_l,
    const float* __restrict__ W_r, const float* __restrict__ cw1,
    _Float16* __restrict__ Wt, float* __restrict__ visitSumB) {
  const int visitRel[5] = {0, 3, 5, 7, 9};
  const int inRel[5] = {1, 2, 4, 6, 8};
  int gid = blockIdx.x * 256 + threadIdx.x;
  if (gid < 1048576) {
    int l = gid >> 18, o = gid & 262143;
    float val; size_t base; int n, k, Kpad;
    if (o < 163840) {          // small stacks, K=256
      int t = o >> 15, e = o & 32767;
      k = e >> 7; n = e & 127; Kpad = 264;
      int r = inRel[t];
      val = (k < 128) ? W_l[(size_t)(l * 10 + r) * 16384 + k * 128 + n]
                      : W_r[(size_t)(l * 10 + r) * 16384 + (k - 128) * 128 + n];
      base = (size_t)l * PLW + t * 67584;
    } else if (o < 245760) {   // trans Wl, K=128
      int q = (o - 163840) >> 14, e = (o - 163840) & 16383;
      k = e >> 7; n = e & 127; Kpad = 136;
      val = W_l[(size_t)(l * 10 + visitRel[q]) * 16384 + k * 128 + n];
      base = (size_t)l * PLW + 337920 + q * 34816;
    } else {                   // SumWr, K=128
      int e = o - 245760;
      k = e >> 7; n = e & 127; Kpad = 136;
      val = 0.f;
      #pragma unroll
      for (int q = 0; q < 5; ++q)
        val += W_r[(size_t)(l * 10 + visitRel[q]) * 16384 + k * 128 + n];
      base = (size_t)l * PLW + 512000;
    }
    _Float16 h = (_Float16)val;
    _Float16 lo = (_Float16)(val - (float)h);
    Wt[base + (size_t)n * Kpad + k] = h;
    Wt[base + (size_t)(128 + n) * Kpad + k] = lo;
  } else if (gid < 1081344) {  // cls W1, K=256
    int e = gid - 1048576;
    int k = e >> 7, n = e & 127;
    float val = cw1[(size_t)k * 128 + n];
    _Float16 h = (_Float16)val;
    _Float16 lo = (_Float16)(val - (float)h);
    size_t base = (size_t)4 * PLW;
    Wt[base + (size_t)n * 264 + k] = h;
    Wt[base + (size_t)(128 + n) * 264 + k] = lo;
  } else if (gid < 1081856) {  // visit summed bias
    int e = gid - 1081344;
    int l = e >> 7, c = e & 127;
    float val = 0.f;
    #pragma unroll
    for (int q = 0; q < 5; ++q) val += b_l[(l * 10 + visitRel[q]) * 128 + c];
    visitSumB[e] = val;
  }
}

// ---------------- small-dst means: 16 lanes x f16x8, 16 rows/block ---------
__global__ __launch_bounds__(256) void agg_small(AggMeta m,
                                                 const _Float16* __restrict__ xv16,
                                                 const int* __restrict__ esrc) {
  int t = blockIdx.y;
  int row = blockIdx.x * 16 + (threadIdx.x >> 4);
  if (row >= m.M[t]) return;
  int q = threadIdx.x & 15;
  const int* rp = m.rp[t];
  int e0 = rp[row], e1 = rp[row + 1];
  float a[8];
  #pragma unroll
  for (int j = 0; j < 8; ++j) a[j] = 0.f;
  int e = e0;
  for (; e + 4 <= e1; e += 4) {
    int s0 = esrc[e], s1 = esrc[e + 1], s2 = esrc[e + 2], s3 = esrc[e + 3];
    f16x8 v0 = *(const f16x8*)(xv16 + (size_t)s0 * 128 + q * 8);
    f16x8 v1 = *(const f16x8*)(xv16 + (size_t)s1 * 128 + q * 8);
    f16x8 v2 = *(const f16x8*)(xv16 + (size_t)s2 * 128 + q * 8);
    f16x8 v3 = *(const f16x8*)(xv16 + (size_t)s3 * 128 + q * 8);
    #pragma unroll
    for (int j = 0; j < 8; ++j)
      a[j] += ((float)v0[j] + (float)v1[j]) + ((float)v2[j] + (float)v3[j]);
  }
  for (; e < e1; ++e) {
    int s = esrc[e];
    f16x8 v = *(const f16x8*)(xv16 + (size_t)s * 128 + q * 8);
    #pragma unroll
    for (int j = 0; j < 8; ++j) a[j] += (float)v[j];
  }
  float inv = (e1 > e0) ? 1.f / (float)(e1 - e0) : 0.f;
  float* o = m.mean[t] + (size_t)row * 128 + q * 8;
  *(float4*)o = make_float4(a[0] * inv, a[1] * inv, a[2] * inv, a[3] * inv);
  *(float4*)(o + 4) = make_float4(a[4] * inv, a[5] * inv, a[6] * inv, a[7] * inv);
}

// ---------------- visit agg: 16 lanes x f16x8, 16 rows/block ---------------
__global__ __launch_bounds__(256) void agg_visit(VAggMeta va, const int* __restrict__ esrc,
                                                 float* __restrict__ xv,
                                                 _Float16* __restrict__ xv16, int doRelu) {
  int row = blockIdx.x * 16 + (threadIdx.x >> 4);
  if (row >= NVISIT) return;
  int q = threadIdx.x & 15;
  float* op = xv + (size_t)row * 128 + q * 8;
  float4 o0 = *(float4*)op;
  float4 o1 = *(float4*)(op + 4);
  float a[8] = {o0.x, o0.y, o0.z, o0.w, o1.x, o1.y, o1.z, o1.w};
  #pragma unroll
  for (int r = 0; r < 5; ++r) {
    int e0 = va.rp[r][row], e1 = va.rp[r][row + 1];
    if (e1 > e0) {
      const _Float16* Y = va.Y[r];
      float s[8];
      #pragma unroll
      for (int j = 0; j < 8; ++j) s[j] = 0.f;
      int e = e0;
      for (; e + 4 <= e1; e += 4) {
        int s0 = esrc[e], s1 = esrc[e + 1], s2 = esrc[e + 2], s3 = esrc[e + 3];
        f16x8 v0 = *(const f16x8*)(Y + (size_t)s0 * 128 + q * 8);
        f16x8 v1 = *(const f16x8*)(Y + (size_t)s1 * 128 + q * 8);
        f16x8 v2 = *(const f16x8*)(Y + (size_t)s2 * 128 + q * 8);
        f16x8 v3 = *(const f16x8*)(Y + (size_t)s3 * 128 + q * 8);
        #pragma unroll
        for (int j = 0; j < 8; ++j)
          s[j] += ((float)v0[j] + (float)v1[j]) + ((float)v2[j] + (float)v3[j]);
      }
      for (; e < e1; ++e) {
        int si = esrc[e];
        f16x8 v = *(const f16x8*)(Y + (size_t)si * 128 + q * 8);
        #pragma unroll
        for (int j = 0; j < 8; ++j) s[j] += (float)v[j];
      }
      float inv = 1.f / (float)(e1 - e0);
      #pragma unroll
      for (int j = 0; j < 8; ++j) a[j] += s[j] * inv;
    }
  }
  if (doRelu) {
    #pragma unroll
    for (int j = 0; j < 8; ++j) a[j] = fmaxf(a[j], 0.f);
  }
  *(float4*)op = make_float4(a[0], a[1], a[2], a[3]);
  *(float4*)(op + 4) = make_float4(a[4], a[5], a[6], a[7]);
  f16x8 h;
  #pragma unroll
  for (int j = 0; j < 8; ++j) h[j] = (_Float16)a[j];
  *(f16x8*)(xv16 + (size_t)row * 128 + q * 8) = h;
}

// ---------------- MFMA f16x3 GEMM, multi-task ------------------------------
// BM=BN=128, BK=64, 256 thr = 4 waves (2x2 of 64x64), 16x16x32 tiles.
__global__ __launch_bounds__(256, 2) void mgemm(MMeta mm) {
  int b = blockIdx.x;
  int ti = 0;
  for (int i = 1; i < mm.nTasks; ++i) if (b >= mm.t[i].blkOff) ti = i;
  MTask tk = mm.t[ti];
  int blockRow = (b - tk.blkOff) * 128;
  int Kpad = tk.K + 8;

  __shared__ _Float16 Ash[2][128][72];
  int tid = threadIdx.x;
  int wave = tid >> 6, lane = tid & 63;
  int quad = lane >> 4, lm = lane & 15;
  int wr = wave >> 1, wc = wave & 1;

  f32x4 acc[4][4];
  #pragma unroll
  for (int i = 0; i < 4; ++i)
    #pragma unroll
    for (int j = 0; j < 4; ++j) acc[i][j] = (f32x4){0.f, 0.f, 0.f, 0.f};

  const _Float16* wrowH[4];
  const _Float16* wrowL[4];
  #pragma unroll
  for (int nt = 0; nt < 4; ++nt) {
    int n = wc * 64 + nt * 16 + lm;
    wrowH[nt] = tk.W + (size_t)n * Kpad;
    wrowL[nt] = tk.W + (size_t)(128 + n) * Kpad;
  }

  int sr = tid >> 1, sk = (tid & 1) * 32;
  for (int k0 = 0; k0 < tk.K; k0 += 64) {
    const float* Asrc = (k0 < 128) ? tk.A0 : tk.A1;
    int ak0 = (k0 & 127) + sk;
    int gr = blockRow + sr;
    if (gr < tk.M) {
      const float* p = Asrc + (size_t)gr * 128 + ak0;
      #pragma unroll
      for (int c = 0; c < 8; ++c) {
        float4 v = *(const float4*)(p + c * 4);
        f16x4 hv, lv;
        hv[0] = (_Float16)v.x; hv[1] = (_Float16)v.y;
        hv[2] = (_Float16)v.z; hv[3] = (_Float16)v.w;
        lv[0] = (_Float16)(v.x - (float)hv[0]);
        lv[1] = (_Float16)(v.y - (float)hv[1]);
        lv[2] = (_Float16)(v.z - (float)hv[2]);
        lv[3] = (_Float16)(v.w - (float)hv[3]);
        *(f16x4*)&Ash[0][sr][sk + c * 4] = hv;
        *(f16x4*)&Ash[1][sr][sk + c * 4] = lv;
      }
    } else {
      f16x4 z = (f16x4){(_Float16)0.f, (_Float16)0.f, (_Float16)0.f, (_Float16)0.f};
      #pragma unroll
      for (int c = 0; c < 8; ++c) {
        *(f16x4*)&Ash[0][sr][sk + c * 4] = z;
        *(f16x4*)&Ash[1][sr][sk + c * 4] = z;
      }
    }
    __syncthreads();
    #pragma unroll
    for (int ks = 0; ks < 64; ks += 32) {
      int kf = k0 + ks + quad * 8;
      f16x8 bh[4], bl[4];
      #pragma unroll
      for (int nt = 0; nt < 4; ++nt) {
        bh[nt] = *(const f16x8*)(wrowH[nt] + kf);
        bl[nt] = *(const f16x8*)(wrowL[nt] + kf);
      }
      #pragma unroll
      for (int mt = 0; mt < 4; ++mt) {
        int r = wr * 64 + mt * 16 + lm;
        f16x8 ah = *(const f16x8*)&Ash[0][r][ks + quad * 8];
        f16x8 al = *(const f16x8*)&Ash[1][r][ks + quad * 8];
        #pragma unroll
        for (int nt = 0; nt < 4; ++nt) {
          acc[mt][nt] = __builtin_amdgcn_mfma_f32_16x16x32_f16(ah, bh[nt], acc[mt][nt], 0, 0, 0);
          acc[mt][nt] = __builtin_amdgcn_mfma_f32_16x16x32_f16(ah, bl[nt], acc[mt][nt], 0, 0, 0);
          acc[mt][nt] = __builtin_amdgcn_mfma_f32_16x16x32_f16(al, bh[nt], acc[mt][nt], 0, 0, 0);
        }
      }
    }
    __syncthreads();
  }

  float bv[4];
  #pragma unroll
  for (int nt = 0; nt < 4; ++nt)
    bv[nt] = tk.bias ? tk.bias[wc * 64 + nt * 16 + lm] : 0.f;
  #pragma unroll
  for (int mt = 0; mt < 4; ++mt) {
    #pragma unroll
    for (int i = 0; i < 4; ++i) {
      int grow = blockRow + wr * 64 + mt * 16 + quad * 4 + i;
      if (grow >= tk.M) continue;
      float v[4];
      #pragma unroll
      for (int nt = 0; nt < 4; ++nt) {
        v[nt] = acc[mt][nt][i] + bv[nt];
        if (tk.relu) v[nt] = fmaxf(v[nt], 0.f);
      }
      if (tk.out) {
        float* orow = tk.out + (size_t)grow * 128 + wc * 64 + lm;
        #pragma unroll
        for (int nt = 0; nt < 4; ++nt) orow[nt * 16] = v[nt];
      }
      if (tk.out16) {
        _Float16* o2 = tk.out16 + (size_t)grow * 128 + wc * 64 + lm;
        #pragma unroll
        for (int nt = 0; nt < 4; ++nt) o2[nt * 16] = (_Float16)v[nt];
      }
    }
  }
}

// ---------------- MFMA classifier (f16 A from gather tables, f16x2 B) ------
__global__ __launch_bounds__(256, 2) void mgemm_cls(
    const _Float16* __restrict__ xv16, const _Float16* __restrict__ xd16,
    const int* __restrict__ eli, const _Float16* __restrict__ W,  // [2][128][264]
    const float* __restrict__ b1, const float* __restrict__ w2,
    const float* __restrict__ b2, const float* __restrict__ y,
    float* __restrict__ lossOut, float* __restrict__ pred, int M) {
  __shared__ _Float16 Ash[128][72];
  __shared__ int idxA[128];
  __shared__ int idxB[128];
  __shared__ float predPart[128];
  __shared__ float redL[128];
  int tid = threadIdx.x;
  int wave = tid >> 6, lane = tid & 63;
  int quad = lane >> 4, lm = lane & 15;
  int wr = wave >> 1, wc = wave & 1;
  int blockRow = blockIdx.x * 128;
  if (tid < 128) {
    int gr = blockRow + tid;
    idxA[tid] = (gr < M) ? eli[gr] : 0;
  } else {
    int t2 = tid - 128;
    int gr = blockRow + t2;
    idxB[t2] = (gr < M) ? eli[M + gr] : 0;
  }
  f32x4 acc[4][4];
  #pragma unroll
  for (int i = 0; i < 4; ++i)
    #pragma unroll
    for (int j = 0; j < 4; ++j) acc[i][j] = (f32x4){0.f, 0.f, 0.f, 0.f};

  const _Float16* wrowH[4];
  const _Float16* wrowL[4];
  #pragma unroll
  for (int nt = 0; nt < 4; ++nt) {
    int n = wc * 64 + nt * 16 + lm;
    wrowH[nt] = W + (size_t)n * 264;
    wrowL[nt] = W + (size_t)(128 + n) * 264;
  }
  __syncthreads();

  int sr = tid >> 1, sk = (tid & 1) * 32;
  for (int k0 = 0; k0 < 256; k0 += 64) {
    const _Float16* base = (k0 < 128) ? xv16 : xd16;
    int srcRow = (k0 < 128) ? idxA[sr] : idxB[sr];
    const _Float16* p = base + (size_t)srcRow * 128 + (k0 & 127) + sk;
    #pragma unroll
    for (int c = 0; c < 4; ++c)
      *(f16x8*)&Ash[sr][sk + c * 8] = *(const f16x8*)(p + c * 8);
    __syncthreads();
    #pragma unroll
    for (int ks = 0; ks < 64; ks += 32) {
      int kf = k0 + ks + quad * 8;
      f16x8 bh[4], bl[4];
      #pragma unroll
      for (int nt = 0; nt < 4; ++nt) {
        bh[nt] = *(const f16x8*)(wrowH[nt] + kf);
        bl[nt] = *(const f16x8*)(wrowL[nt] + kf);
      }
      #pragma unroll
      for (int mt = 0; mt < 4; ++mt) {
        int r = wr * 64 + mt * 16 + lm;
        f16x8 ah = *(const f16x8*)&Ash[r][ks + quad * 8];
        #pragma unroll
        for (int nt = 0; nt < 4; ++nt) {
          acc[mt][nt] = __builtin_amdgcn_mfma_f32_16x16x32_f16(ah, bh[nt], acc[mt][nt], 0, 0, 0);
          acc[mt][nt] = __builtin_amdgcn_mfma_f32_16x16x32_f16(ah, bl[nt], acc[mt][nt], 0, 0, 0);
        }
      }
    }
    __syncthreads();
  }

  float b1v[4], w2v[4];
  #pragma unroll
  for (int nt = 0; nt < 4; ++nt) {
    int col = wc * 64 + nt * 16 + lm;
    b1v[nt] = b1[col];
    w2v[nt] = w2[col];
  }
  float rowp[4][4];
  #pragma unroll
  for (int mt = 0; mt < 4; ++mt)
    #pragma unroll
    for (int i = 0; i < 4; ++i) {
      float p = 0.f;
      #pragma unroll
      for (int nt = 0; nt < 4; ++nt)
        p += fmaxf(acc[mt][nt][i] + b1v[nt], 0.f) * w2v[nt];
      p += __shfl_xor(p, 1);
      p += __shfl_xor(p, 2);
      p += __shfl_xor(p, 4);
      p += __shfl_xor(p, 8);
      rowp[mt][i] = p;
    }
  if (wc == 0 && lm == 0) {
    #pragma unroll
    for (int mt = 0; mt < 4; ++mt)
      #pragma unroll
      for (int i = 0; i < 4; ++i)
        predPart[wr * 64 + mt * 16 + quad * 4 + i] = rowp[mt][i];
  }
  __syncthreads();
  if (wc == 1 && lm == 0) {
    #pragma unroll
    for (int mt = 0; mt < 4; ++mt)
      #pragma unroll
      for (int i = 0; i < 4; ++i)
        predPart[wr * 64 + mt * 16 + quad * 4 + i] += rowp[mt][i];
  }
  __syncthreads();
  if (tid < 128) {
    int gr = blockRow + tid;
    float lv = 0.f;
    if (gr < M) {
      float z = predPart[tid] + b2[0];
      pred[gr] = z;
      lv = fmaxf(z, 0.f) + log1pf(expf(-fabsf(z))) - z * y[gr];
    }
    redL[tid] = lv;
  }
  __syncthreads();
  if (tid == 0) {
    float s = 0.f;
    for (int i = 0; i < 128; ++i) s += redL[i];
    atomicAdd(lossOut, s * (1.0f / 200000.0f));
  }
}

// ---------------------------------------------------------------------------
extern "C" void kernel_launch(void* const* d_in, const int* in_sizes, int n_in,
                              void* d_out, int out_size, void* d_ws, size_t ws_size,
                              hipStream_t stream) {
  static const int kRows[6] = {20000, 100000, 4000, 8000, 10000, 4000};
  static const int kOff[6]  = {0, 20000, 120000, 124000, 132000, 142000};
  static const int kSmallT[5]   = {0, 2, 3, 4, 5};
  static const int kInRel[5]    = {1, 2, 4, 6, 8};
  static const int kCbcIn[5]    = {100000, 120000, 224000, 332000, 442000};
  static const int kCbcVisit[5] = {0, 124000, 232000, 342000, 446000};
  static const int kYOff[5]     = {0, 20000, 24000, 32000, 42000};
  static const int kBOff[5]     = {0, 157, 189, 252, 331};
  static const int kCbcA[NREL]  = {0, 100000, 120000, 124000, 224000,
                                   232000, 332000, 342000, 442000, 446000};
  static const int kEhA[NREL]   = {100000, 100000, 300000, 300000, 200000,
                                   200000, 250000, 250000, 300000, 300000};
  static const int kNdst[NREL]  = {100000, 20000, 4000, 100000, 8000,
                                   100000, 10000, 100000, 4000, 100000};

  const float* W_l = (const float*)d_in[22];
  const float* b_l = (const float*)d_in[23];
  const float* W_r = (const float*)d_in[24];
  const float* cw1 = (const float*)d_in[25];
  const float* cb1 = (const float*)d_in[26];
  const float* cw2 = (const float*)d_in[27];
  const float* cb2 = (const float*)d_in[28];
  const int* eli = (const int*)d_in[29];
  const float* ylab = (const float*)d_in[30];

  // workspace layout (single x buffer; in-place layer update)
  float* x = (float*)d_ws;                           // 146000*128 fp32
  float* meanS = x + 146000UL * 128UL;               // 46000*128 fp32
  int* prefix = (int*)(meanS + 46000UL * 128UL);     // 546,004 ints
  int* counts = prefix + 546004;                     // 546,000 ints (cursor)
  int* esrc = counts + NCOUNTS;                      // 2,300,000 ints
  int* partials = esrc + NEDGES;                     // 1,024 ints
  float* visitSumB = (float*)(partials + 1024);      // 512 floats
  _Float16* Wt = (_Float16*)(visitSumB + 512);       // WT_ELEMS f16
  _Float16* xv16 = Wt + WT_ELEMS;                    // 100000*128 f16
  _Float16* Y16 = xv16 + 100000UL * 128UL;           // 46000*128 f16
  _Float16* drug16 = Y16 + 46000UL * 128UL;          // 4000*128 f16

  RelMeta rm;
  for (int r = 0; r < NREL; ++r) {
    rm.ei[r] = (const int*)d_in[12 + r];
    rm.E[r] = kEhA[r];
    rm.cbc[r] = kCbcA[r];
    rm.scl[r] = 8.0f / (float)kNdst[r];
  }

  hipMemsetAsync(counts, 0, NCOUNTS * sizeof(int), stream);
  hipMemsetAsync(d_out, 0, sizeof(float), stream);

  prep_split<<<(1081856 + 255) / 256, 256, 0, stream>>>(W_l, b_l, W_r, cw1, Wt, visitSumB);

  GatherMeta gm;
  for (int t = 0; t < 6; ++t) {
    gm.nid[t] = (const int*)d_in[2 * t];
    gm.emb[t] = (const float*)d_in[2 * t + 1];
    gm.rows[t] = kRows[t];
    gm.off[t] = kOff[t];
  }
  gather_all<<<dim3(12500, 6), 256, 0, stream>>>(gm, x, xv16);

  // CSR build: XCD-ranged hist -> scan -> XCD-ranged scatter
  dim3 egrid(1172 * 8, NREL);
  hist_ranged<<<egrid, 256, 0, stream>>>(rm, counts);
  scan1<<<534, 1024, 0, stream>>>(counts, partials);
  scan2<<<1, 1024, 0, stream>>>(partials, 534);
  scan3<<<534, 1024, 0, stream>>>(counts, prefix, partials);
  scatter_ranged<<<egrid, 256, 0, stream>>>(rm, counts, esrc);

  for (int l = 0; l < 4; ++l) {
    int doRelu = (l < 3);
    int last = (l == 3);
    _Float16* LW = Wt + (size_t)l * PLW;

    // 1) small-dst means from f16 x_v (layer 3: drug only)
    AggMeta am;
    if (!last) {
      for (int t = 0; t < 5; ++t) {
        am.rp[t] = prefix + kCbcIn[t];
        am.mean[t] = meanS + (size_t)kYOff[t] * 128;
        am.M[t] = kRows[kSmallT[t]];
      }
      agg_small<<<dim3(1250, 5), 256, 0, stream>>>(am, xv16, esrc);
    } else {
      am.rp[0] = prefix + kCbcIn[4];
      am.mean[0] = meanS + (size_t)kYOff[4] * 128;
      am.M[0] = 4000;
      agg_small<<<dim3(250, 1), 256, 0, stream>>>(am, xv16, esrc);
    }

    // 2) m2: Y_q = x_src @ Wl_q (f16 out) ; x_v = x_v @ SumWr + Sumb (in-place)
    MMeta m2;
    m2.nTasks = 6;
    for (int q = 0; q < 5; ++q) {
      m2.t[q].A0 = x + (size_t)kOff[kSmallT[q]] * 128;
      m2.t[q].A1 = nullptr;
      m2.t[q].W = LW + 337920 + (size_t)q * 34816;
      m2.t[q].bias = nullptr;
      m2.t[q].out = nullptr;
      m2.t[q].out16 = Y16 + (size_t)kYOff[q] * 128;
      m2.t[q].M = kRows[kSmallT[q]];
      m2.t[q].blkOff = kBOff[q];
      m2.t[q].K = 128;
      m2.t[q].relu = 0;
    }
    m2.t[5].A0 = x + (size_t)kOff[1] * 128;
    m2.t[5].A1 = nullptr;
    m2.t[5].W = LW + 512000;
    m2.t[5].bias = visitSumB + l * 128;
    m2.t[5].out = x + (size_t)kOff[1] * 128;   // in-place (block-local rows)
    m2.t[5].out16 = nullptr;
    m2.t[5].M = NVISIT;
    m2.t[5].blkOff = 363;
    m2.t[5].K = 128;
    m2.t[5].relu = 0;
    mgemm<<<dim3(363 + 782), 256, 0, stream>>>(m2);

    // 3) m1: small-dst [mean | x_old] @ [Wl;Wr] + b, in-place (l3: drug only)
    MMeta m1;
    if (!last) {
      m1.nTasks = 5;
      for (int t = 0; t < 5; ++t) {
        m1.t[t].A0 = meanS + (size_t)kYOff[t] * 128;
        m1.t[t].A1 = x + (size_t)kOff[kSmallT[t]] * 128;
        m1.t[t].W = LW + (size_t)t * 67584;
        m1.t[t].bias = b_l + (size_t)(l * 10 + kInRel[t]) * 128;
        m1.t[t].out = x + (size_t)kOff[kSmallT[t]] * 128;
        m1.t[t].out16 = nullptr;
        m1.t[t].M = kRows[kSmallT[t]];
        m1.t[t].blkOff = kBOff[t];
        m1.t[t].K = 256;
        m1.t[t].relu = doRelu;
      }
      mgemm<<<dim3(363), 256, 0, stream>>>(m1);
    } else {
      m1.nTasks = 1;
      m1.t[0].A0 = meanS + (size_t)kYOff[4] * 128;
      m1.t[0].A1 = x + (size_t)kOff[5] * 128;
      m1.t[0].W = LW + (size_t)4 * 67584;
      m1.t[0].bias = b_l + (size_t)(l * 10 + kInRel[4]) * 128;
      m1.t[0].out = nullptr;
      m1.t[0].out16 = drug16;
      m1.t[0].M = 4000;
      m1.t[0].blkOff = 0;
      m1.t[0].K = 256;
      m1.t[0].relu = 0;
      mgemm<<<dim3(32), 256, 0, stream>>>(m1);
    }

    // 4) x_v += sum_r mean_r(Y16_r); relu; refresh f16 copy
    VAggMeta va;
    for (int q = 0; q < 5; ++q) {
      va.rp[q] = prefix + kCbcVisit[q];
      va.Y[q] = Y16 + (size_t)kYOff[q] * 128;
    }
    agg_visit<<<dim3(6250), 256, 0, stream>>>(va, esrc, x + (size_t)kOff[1] * 128,
                                              xv16, doRelu);
  }

  const int ML = 200000;
  mgemm_cls<<<dim3((ML + 127) / 128), 256, 0, stream>>>(
      xv16, drug16, eli, Wt + (size_t)4 * PLW, cb1, cw2, cb2, ylab,
      (float*)d_out, (float*)d_out + 1, ML);
}

// Round 8
// 1156.525 us; speedup vs baseline: 1.1298x; 1.1298x over previous
//
#include <hip/hip_runtime.h>
#include <cmath>

// ---------------------------------------------------------------------------
// Hetero-SAGE GNN (4 layers, 10 relations, D=128) + edge classifier.
// R8: split-f16 feature planes H,L (x = H+L, 22-bit): no fp32 x master.
//  - conv0: emb -> H/L (replaces gather_all; no fp32 x buffer anywhere)
//  - mgemm: A staged as raw H/L copies (no cvt VALU), f16x3 MFMA
//  - agg_visit: RMW on H/L (4B/elem vs 6B) -> ~75MB/layer saved
//  - CSR build reverted to R6 hist+scan+scatter (R7 ranged build regressed:
//    8x edge re-read, XCD mapping assumption only partially held)
// Carried: per-dst-type fused GEMMs, transform-before-aggregate, h-only Y and
// h-only gathers in agg_small/cls, in-place updates, layer-3 pruning.
// ---------------------------------------------------------------------------

typedef _Float16 f16x8 __attribute__((ext_vector_type(8)));
typedef _Float16 f16x4 __attribute__((ext_vector_type(4)));
typedef float f32x4 __attribute__((ext_vector_type(4)));

#define NREL 10
#define NCOUNTS 546000
#define NEDGES  2300000
#define NVISIT  100000
#define PLW 546816
#define WT_ELEMS (4 * PLW + 67584)
#define XELEMS 18688000UL   // 146000*128
#define SELEMS 5888000UL    // 46000*128

struct RelMeta { const int* ei[NREL]; int E[NREL]; int cbc[NREL]; };
struct GatherMeta { const float* emb[6]; const int* nid[6]; int rows[6]; int off[6]; };
struct AggMeta { const int* rp[5]; _Float16* meanH[5]; _Float16* meanL[5]; int M[5]; };
struct VAggMeta { const int* rp[5]; const _Float16* Y[5]; };
struct MTask {
  const _Float16* AH0; const _Float16* AL0;  // k in [0,128)
  const _Float16* AH1; const _Float16* AL1;  // k in [128,256)
  const _Float16* W;                         // [2][128][Kpad] h then l plane
  const float* bias;                         // nullable
  _Float16* outH; _Float16* outL;            // outL nullable (h-only output)
  int M, blkOff, K, relu;
};
struct MMeta { MTask t[6]; int nTasks; };

// ---------------- conv0: emb -> split H/L planes ---------------------------
__global__ __launch_bounds__(256) void conv0(GatherMeta g, _Float16* __restrict__ H,
                                             _Float16* __restrict__ L) {
  int t = blockIdx.y;
  int i = blockIdx.x * 256 + threadIdx.x;
  if (i >= g.rows[t] * 16) return;
  int row = i >> 4, q = i & 15;
  int s = g.nid[t][row];
  const float* p = g.emb[t] + (size_t)s * 128 + q * 8;
  float4 v0 = *(const float4*)p;
  float4 v1 = *(const float4*)(p + 4);
  float v[8] = {v0.x, v0.y, v0.z, v0.w, v1.x, v1.y, v1.z, v1.w};
  f16x8 h, l;
  #pragma unroll
  for (int j = 0; j < 8; ++j) {
    h[j] = (_Float16)v[j];
    l[j] = (_Float16)(v[j] - (float)h[j]);
  }
  size_t o = (size_t)(g.off[t] + row) * 128 + q * 8;
  *(f16x8*)(H + o) = h;
  *(f16x8*)(L + o) = l;
}

// ---------------- CSR build (R6 form) --------------------------------------
__global__ __launch_bounds__(256) void hist_kernel(RelMeta m, int* __restrict__ counts) {
  int r = blockIdx.y;
  int e = blockIdx.x * 256 + threadIdx.x;
  if (e >= m.E[r]) return;
  int c = m.ei[r][m.E[r] + e];
  atomicAdd(&counts[m.cbc[r] + c], 1);
}

__global__ __launch_bounds__(1024) void scan1(const int* __restrict__ counts,
                                              int* __restrict__ partials) {
  __shared__ int s[1024];
  int i = blockIdx.x * 1024 + threadIdx.x;
  s[threadIdx.x] = (i < NCOUNTS) ? counts[i] : 0;
  __syncthreads();
  for (int off = 512; off > 0; off >>= 1) {
    if (threadIdx.x < off) s[threadIdx.x] += s[threadIdx.x + off];
    __syncthreads();
  }
  if (threadIdx.x == 0) partials[blockIdx.x] = s[0];
}

__global__ __launch_bounds__(1024) void scan2(int* __restrict__ partials, int nb) {
  __shared__ int s[1024];
  int t = threadIdx.x;
  int v = (t < nb) ? partials[t] : 0;
  s[t] = v;
  __syncthreads();
  for (int off = 1; off < 1024; off <<= 1) {
    int add = (t >= off) ? s[t - off] : 0;
    __syncthreads();
    s[t] += add;
    __syncthreads();
  }
  if (t < nb) partials[t] = s[t] - v;  // exclusive
}

__global__ __launch_bounds__(1024) void scan3(int* __restrict__ counts,
                                              int* __restrict__ prefix,
                                              const int* __restrict__ partials) {
  __shared__ int s[1024];
  int t = threadIdx.x;
  int i = blockIdx.x * 1024 + t;
  int v = (i < NCOUNTS) ? counts[i] : 0;
  s[t] = v;
  __syncthreads();
  for (int off = 1; off < 1024; off <<= 1) {
    int add = (t >= off) ? s[t - off] : 0;
    __syncthreads();
    s[t] += add;
    __syncthreads();
  }
  int P = partials[blockIdx.x] + s[t] - v;
  if (i < NCOUNTS) { prefix[i] = P; counts[i] = P; /* cursor */ }
  if (blockIdx.x == 0 && t == 0) prefix[NCOUNTS] = NEDGES;
}

__global__ __launch_bounds__(256) void scatter_kernel(RelMeta m, int* __restrict__ cursor,
                                                      int* __restrict__ esrc) {
  int r = blockIdx.y;
  int e = blockIdx.x * 256 + threadIdx.x;
  if (e >= m.E[r]) return;
  const int* ei = m.ei[r];
  int c = ei[m.E[r] + e];
  int pos = atomicAdd(&cursor[m.cbc[r] + c], 1);
  esrc[pos] = ei[e];
}

// ---------------- weight split/transpose prep ------------------------------
__global__ __launch_bounds__(256) void prep_split(
    const float* __restrict__ W_l, const float* __restrict__ b_l,
    const float* __restrict__ W_r, const float* __restrict__ cw1,
    _Float16* __restrict__ Wt, float* __restrict__ visitSumB) {
  const int visitRel[5] = {0, 3, 5, 7, 9};
  const int inRel[5] = {1, 2, 4, 6, 8};
  int gid = blockIdx.x * 256 + threadIdx.x;
  if (gid < 1048576) {
    int l = gid >> 18, o = gid & 262143;
    float val; size_t base; int n, k, Kpad;
    if (o < 163840) {          // small stacks, K=256
      int t = o >> 15, e = o & 32767;
      k = e >> 7; n = e & 127; Kpad = 264;
      int r = inRel[t];
      val = (k < 128) ? W_l[(size_t)(l * 10 + r) * 16384 + k * 128 + n]
                      : W_r[(size_t)(l * 10 + r) * 16384 + (k - 128) * 128 + n];
      base = (size_t)l * PLW + t * 67584;
    } else if (o < 245760) {   // trans Wl, K=128
      int q = (o - 163840) >> 14, e = (o - 163840) & 16383;
      k = e >> 7; n = e & 127; Kpad = 136;
      val = W_l[(size_t)(l * 10 + visitRel[q]) * 16384 + k * 128 + n];
      base = (size_t)l * PLW + 337920 + q * 34816;
    } else {                   // SumWr, K=128
      int e = o - 245760;
      k = e >> 7; n = e & 127; Kpad = 136;
      val = 0.f;
      #pragma unroll
      for (int q = 0; q < 5; ++q)
        val += W_r[(size_t)(l * 10 + visitRel[q]) * 16384 + k * 128 + n];
      base = (size_t)l * PLW + 512000;
    }
    _Float16 h = (_Float16)val;
    _Float16 lo = (_Float16)(val - (float)h);
    Wt[base + (size_t)n * Kpad + k] = h;
    Wt[base + (size_t)(128 + n) * Kpad + k] = lo;
  } else if (gid < 1081344) {  // cls W1, K=256
    int e = gid - 1048576;
    int k = e >> 7, n = e & 127;
    float val = cw1[(size_t)k * 128 + n];
    _Float16 h = (_Float16)val;
    _Float16 lo = (_Float16)(val - (float)h);
    size_t base = (size_t)4 * PLW;
    Wt[base + (size_t)n * 264 + k] = h;
    Wt[base + (size_t)(128 + n) * 264 + k] = lo;
  } else if (gid < 1081856) {  // visit summed bias
    int e = gid - 1081344;
    int l = e >> 7, c = e & 127;
    float val = 0.f;
    #pragma unroll
    for (int q = 0; q < 5; ++q) val += b_l[(l * 10 + visitRel[q]) * 128 + c];
    visitSumB[e] = val;
  }
}

// ---------------- small-dst means: gather H(visit), write split means ------
__global__ __launch_bounds__(256) void agg_small(AggMeta m,
                                                 const _Float16* __restrict__ xvH,
                                                 const int* __restrict__ esrc) {
  int t = blockIdx.y;
  int row = blockIdx.x * 16 + (threadIdx.x >> 4);
  if (row >= m.M[t]) return;
  int q = threadIdx.x & 15;
  const int* rp = m.rp[t];
  int e0 = rp[row], e1 = rp[row + 1];
  float a[8];
  #pragma unroll
  for (int j = 0; j < 8; ++j) a[j] = 0.f;
  int e = e0;
  for (; e + 4 <= e1; e += 4) {
    int s0 = esrc[e], s1 = esrc[e + 1], s2 = esrc[e + 2], s3 = esrc[e + 3];
    f16x8 v0 = *(const f16x8*)(xvH + (size_t)s0 * 128 + q * 8);
    f16x8 v1 = *(const f16x8*)(xvH + (size_t)s1 * 128 + q * 8);
    f16x8 v2 = *(const f16x8*)(xvH + (size_t)s2 * 128 + q * 8);
    f16x8 v3 = *(const f16x8*)(xvH + (size_t)s3 * 128 + q * 8);
    #pragma unroll
    for (int j = 0; j < 8; ++j)
      a[j] += ((float)v0[j] + (float)v1[j]) + ((float)v2[j] + (float)v3[j]);
  }
  for (; e < e1; ++e) {
    int s = esrc[e];
    f16x8 v = *(const f16x8*)(xvH + (size_t)s * 128 + q * 8);
    #pragma unroll
    for (int j = 0; j < 8; ++j) a[j] += (float)v[j];
  }
  float inv = (e1 > e0) ? 1.f / (float)(e1 - e0) : 0.f;
  f16x8 h, l;
  #pragma unroll
  for (int j = 0; j < 8; ++j) {
    float v = a[j] * inv;
    h[j] = (_Float16)v;
    l[j] = (_Float16)(v - (float)h[j]);
  }
  size_t o = (size_t)row * 128 + q * 8;
  *(f16x8*)(m.meanH[t] + o) = h;
  *(f16x8*)(m.meanL[t] + o) = l;
}

// ---------------- visit agg: H/L += sum_r mean_r(YH_r); relu; split back ---
__global__ __launch_bounds__(256) void agg_visit(VAggMeta va, const int* __restrict__ esrc,
                                                 _Float16* __restrict__ xvH,
                                                 _Float16* __restrict__ xvL, int doRelu) {
  int row = blockIdx.x * 16 + (threadIdx.x >> 4);
  if (row >= NVISIT) return;
  int q = threadIdx.x & 15;
  size_t o = (size_t)row * 128 + q * 8;
  f16x8 h0 = *(f16x8*)(xvH + o);
  f16x8 l0 = *(f16x8*)(xvL + o);
  float a[8];
  #pragma unroll
  for (int j = 0; j < 8; ++j) a[j] = (float)h0[j] + (float)l0[j];
  #pragma unroll
  for (int r = 0; r < 5; ++r) {
    int e0 = va.rp[r][row], e1 = va.rp[r][row + 1];
    if (e1 > e0) {
      const _Float16* Y = va.Y[r];
      float s[8];
      #pragma unroll
      for (int j = 0; j < 8; ++j) s[j] = 0.f;
      int e = e0;
      for (; e + 4 <= e1; e += 4) {
        int s0 = esrc[e], s1 = esrc[e + 1], s2 = esrc[e + 2], s3 = esrc[e + 3];
        f16x8 v0 = *(const f16x8*)(Y + (size_t)s0 * 128 + q * 8);
        f16x8 v1 = *(const f16x8*)(Y + (size_t)s1 * 128 + q * 8);
        f16x8 v2 = *(const f16x8*)(Y + (size_t)s2 * 128 + q * 8);
        f16x8 v3 = *(const f16x8*)(Y + (size_t)s3 * 128 + q * 8);
        #pragma unroll
        for (int j = 0; j < 8; ++j)
          s[j] += ((float)v0[j] + (float)v1[j]) + ((float)v2[j] + (float)v3[j]);
      }
      for (; e < e1; ++e) {
        int si = esrc[e];
        f16x8 v = *(const f16x8*)(Y + (size_t)si * 128 + q * 8);
        #pragma unroll
        for (int j = 0; j < 8; ++j) s[j] += (float)v[j];
      }
      float inv = 1.f / (float)(e1 - e0);
      #pragma unroll
      for (int j = 0; j < 8; ++j) a[j] += s[j] * inv;
    }
  }
  f16x8 h, l;
  #pragma unroll
  for (int j = 0; j < 8; ++j) {
    float v = doRelu ? fmaxf(a[j], 0.f) : a[j];
    h[j] = (_Float16)v;
    l[j] = (_Float16)(v - (float)h[j]);
  }
  *(f16x8*)(xvH + o) = h;
  *(f16x8*)(xvL + o) = l;
}

// ---------------- MFMA f16x3 GEMM, multi-task, split-plane A ---------------
// BM=BN=128, BK=64, 256 thr = 4 waves (2x2 of 64x64), 16x16x32 tiles.
__global__ __launch_bounds__(256, 2) void mgemm(MMeta mm) {
  int b = blockIdx.x;
  int ti = 0;
  for (int i = 1; i < mm.nTasks; ++i) if (b >= mm.t[i].blkOff) ti = i;
  MTask tk = mm.t[ti];
  int blockRow = (b - tk.blkOff) * 128;
  int Kpad = tk.K + 8;

  __shared__ _Float16 Ash[2][128][72];
  int tid = threadIdx.x;
  int wave = tid >> 6, lane = tid & 63;
  int quad = lane >> 4, lm = lane & 15;
  int wr = wave >> 1, wc = wave & 1;

  f32x4 acc[4][4];
  #pragma unroll
  for (int i = 0; i < 4; ++i)
    #pragma unroll
    for (int j = 0; j < 4; ++j) acc[i][j] = (f32x4){0.f, 0.f, 0.f, 0.f};

  const _Float16* wrowH[4];
  const _Float16* wrowL[4];
  #pragma unroll
  for (int nt = 0; nt < 4; ++nt) {
    int n = wc * 64 + nt * 16 + lm;
    wrowH[nt] = tk.W + (size_t)n * Kpad;
    wrowL[nt] = tk.W + (size_t)(128 + n) * Kpad;
  }

  int sr = tid >> 1, sk = (tid & 1) * 32;
  int gr = blockRow + sr; if (gr >= tk.M) gr = tk.M - 1;  // clamp (dup row ok)
  for (int k0 = 0; k0 < tk.K; k0 += 64) {
    const _Float16* AH = (k0 < 128) ? tk.AH0 : tk.AH1;
    const _Float16* AL = (k0 < 128) ? tk.AL0 : tk.AL1;
    size_t abase = (size_t)gr * 128 + (k0 & 127) + sk;
    #pragma unroll
    for (int c = 0; c < 4; ++c) {
      *(f16x8*)&Ash[0][sr][sk + c * 8] = *(const f16x8*)(AH + abase + c * 8);
      *(f16x8*)&Ash[1][sr][sk + c * 8] = *(const f16x8*)(AL + abase + c * 8);
    }
    __syncthreads();
    #pragma unroll
    for (int ks = 0; ks < 64; ks += 32) {
      int kf = k0 + ks + quad * 8;
      f16x8 bh[4], bl[4];
      #pragma unroll
      for (int nt = 0; nt < 4; ++nt) {
        bh[nt] = *(const f16x8*)(wrowH[nt] + kf);
        bl[nt] = *(const f16x8*)(wrowL[nt] + kf);
      }
      #pragma unroll
      for (int mt = 0; mt < 4; ++mt) {
        int r = wr * 64 + mt * 16 + lm;
        f16x8 ah = *(const f16x8*)&Ash[0][r][ks + quad * 8];
        f16x8 al = *(const f16x8*)&Ash[1][r][ks + quad * 8];
        #pragma unroll
        for (int nt = 0; nt < 4; ++nt) {
          acc[mt][nt] = __builtin_amdgcn_mfma_f32_16x16x32_f16(ah, bh[nt], acc[mt][nt], 0, 0, 0);
          acc[mt][nt] = __builtin_amdgcn_mfma_f32_16x16x32_f16(ah, bl[nt], acc[mt][nt], 0, 0, 0);
          acc[mt][nt] = __builtin_amdgcn_mfma_f32_16x16x32_f16(al, bh[nt], acc[mt][nt], 0, 0, 0);
        }
      }
    }
    __syncthreads();
  }

  float bv[4];
  #pragma unroll
  for (int nt = 0; nt < 4; ++nt)
    bv[nt] = tk.bias ? tk.bias[wc * 64 + nt * 16 + lm] : 0.f;
  #pragma unroll
  for (int mt = 0; mt < 4; ++mt) {
    #pragma unroll
    for (int i = 0; i < 4; ++i) {
      int grow = blockRow + wr * 64 + mt * 16 + quad * 4 + i;
      if (grow >= tk.M) continue;
      size_t ob = (size_t)grow * 128 + wc * 64 + lm;
      #pragma unroll
      for (int nt = 0; nt < 4; ++nt) {
        float v = acc[mt][nt][i] + bv[nt];
        if (tk.relu) v = fmaxf(v, 0.f);
        _Float16 h = (_Float16)v;
        tk.outH[ob + nt * 16] = h;
        if (tk.outL) tk.outL[ob + nt * 16] = (_Float16)(v - (float)h);
      }
    }
  }
}

// ---------------- MFMA classifier (H-plane gathers, f16x2 B) ---------------
__global__ __launch_bounds__(256, 2) void mgemm_cls(
    const _Float16* __restrict__ xv16, const _Float16* __restrict__ xd16,
    const int* __restrict__ eli, const _Float16* __restrict__ W,  // [2][128][264]
    const float* __restrict__ b1, const float* __restrict__ w2,
    const float* __restrict__ b2, const float* __restrict__ y,
    float* __restrict__ lossOut, float* __restrict__ pred, int M) {
  __shared__ _Float16 Ash[128][72];
  __shared__ int idxA[128];
  __shared__ int idxB[128];
  __shared__ float predPart[128];
  __shared__ float redL[128];
  int tid = threadIdx.x;
  int wave = tid >> 6, lane = tid & 63;
  int quad = lane >> 4, lm = lane & 15;
  int wr = wave >> 1, wc = wave & 1;
  int blockRow = blockIdx.x * 128;
  if (tid < 128) {
    int gr = blockRow + tid;
    idxA[tid] = (gr < M) ? eli[gr] : 0;
  } else {
    int t2 = tid - 128;
    int gr = blockRow + t2;
    idxB[t2] = (gr < M) ? eli[M + gr] : 0;
  }
  f32x4 acc[4][4];
  #pragma unroll
  for (int i = 0; i < 4; ++i)
    #pragma unroll
    for (int j = 0; j < 4; ++j) acc[i][j] = (f32x4){0.f, 0.f, 0.f, 0.f};

  const _Float16* wrowH[4];
  const _Float16* wrowL[4];
  #pragma unroll
  for (int nt = 0; nt < 4; ++nt) {
    int n = wc * 64 + nt * 16 + lm;
    wrowH[nt] = W + (size_t)n * 264;
    wrowL[nt] = W + (size_t)(128 + n) * 264;
  }
  __syncthreads();

  int sr = tid >> 1, sk = (tid & 1) * 32;
  for (int k0 = 0; k0 < 256; k0 += 64) {
    const _Float16* base = (k0 < 128) ? xv16 : xd16;
    int srcRow = (k0 < 128) ? idxA[sr] : idxB[sr];
    const _Float16* p = base + (size_t)srcRow * 128 + (k0 & 127) + sk;
    #pragma unroll
    for (int c = 0; c < 4; ++c)
      *(f16x8*)&Ash[sr][sk + c * 8] = *(const f16x8*)(p + c * 8);
    __syncthreads();
    #pragma unroll
    for (int ks = 0; ks < 64; ks += 32) {
      int kf = k0 + ks + quad * 8;
      f16x8 bh[4], bl[4];
      #pragma unroll
      for (int nt = 0; nt < 4; ++nt) {
        bh[nt] = *(const f16x8*)(wrowH[nt] + kf);
        bl[nt] = *(const f16x8*)(wrowL[nt] + kf);
      }
      #pragma unroll
      for (int mt = 0; mt < 4; ++mt) {
        int r = wr * 64 + mt * 16 + lm;
        f16x8 ah = *(const f16x8*)&Ash[r][ks + quad * 8];
        #pragma unroll
        for (int nt = 0; nt < 4; ++nt) {
          acc[mt][nt] = __builtin_amdgcn_mfma_f32_16x16x32_f16(ah, bh[nt], acc[mt][nt], 0, 0, 0);
          acc[mt][nt] = __builtin_amdgcn_mfma_f32_16x16x32_f16(ah, bl[nt], acc[mt][nt], 0, 0, 0);
        }
      }
    }
    __syncthreads();
  }

  float b1v[4], w2v[4];
  #pragma unroll
  for (int nt = 0; nt < 4; ++nt) {
    int col = wc * 64 + nt * 16 + lm;
    b1v[nt] = b1[col];
    w2v[nt] = w2[col];
  }
  float rowp[4][4];
  #pragma unroll
  for (int mt = 0; mt < 4; ++mt)
    #pragma unroll
    for (int i = 0; i < 4; ++i) {
      float p = 0.f;
      #pragma unroll
      for (int nt = 0; nt < 4; ++nt)
        p += fmaxf(acc[mt][nt][i] + b1v[nt], 0.f) * w2v[nt];
      p += __shfl_xor(p, 1);
      p += __shfl_xor(p, 2);
      p += __shfl_xor(p, 4);
      p += __shfl_xor(p, 8);
      rowp[mt][i] = p;
    }
  if (wc == 0 && lm == 0) {
    #pragma unroll
    for (int mt = 0; mt < 4; ++mt)
      #pragma unroll
      for (int i = 0; i < 4; ++i)
        predPart[wr * 64 + mt * 16 + quad * 4 + i] = rowp[mt][i];
  }
  __syncthreads();
  if (wc == 1 && lm == 0) {
    #pragma unroll
    for (int mt = 0; mt < 4; ++mt)
      #pragma unroll
      for (int i = 0; i < 4; ++i)
        predPart[wr * 64 + mt * 16 + quad * 4 + i] += rowp[mt][i];
  }
  __syncthreads();
  if (tid < 128) {
    int gr = blockRow + tid;
    float lv = 0.f;
    if (gr < M) {
      float z = predPart[tid] + b2[0];
      pred[gr] = z;
      lv = fmaxf(z, 0.f) + log1pf(expf(-fabsf(z))) - z * y[gr];
    }
    redL[tid] = lv;
  }
  __syncthreads();
  if (tid == 0) {
    float s = 0.f;
    for (int i = 0; i < 128; ++i) s += redL[i];
    atomicAdd(lossOut, s * (1.0f / 200000.0f));
  }
}

// ---------------------------------------------------------------------------
extern "C" void kernel_launch(void* const* d_in, const int* in_sizes, int n_in,
                              void* d_out, int out_size, void* d_ws, size_t ws_size,
                              hipStream_t stream) {
  static const int kRows[6] = {20000, 100000, 4000, 8000, 10000, 4000};
  static const int kOff[6]  = {0, 20000, 120000, 124000, 132000, 142000};
  static const int kSmallT[5]   = {0, 2, 3, 4, 5};
  static const int kInRel[5]    = {1, 2, 4, 6, 8};
  static const int kCbcIn[5]    = {100000, 120000, 224000, 332000, 442000};
  static const int kCbcVisit[5] = {0, 124000, 232000, 342000, 446000};
  static const int kYOff[5]     = {0, 20000, 24000, 32000, 42000};
  static const int kBOff[5]     = {0, 157, 189, 252, 331};
  static const int kCbcA[NREL]  = {0, 100000, 120000, 124000, 224000,
                                   232000, 332000, 342000, 442000, 446000};
  static const int kEhA[NREL]   = {100000, 100000, 300000, 300000, 200000,
                                   200000, 250000, 250000, 300000, 300000};

  const float* W_l = (const float*)d_in[22];
  const float* b_l = (const float*)d_in[23];
  const float* W_r = (const float*)d_in[24];
  const float* cw1 = (const float*)d_in[25];
  const float* cb1 = (const float*)d_in[26];
  const float* cw2 = (const float*)d_in[27];
  const float* cb2 = (const float*)d_in[28];
  const int* eli = (const int*)d_in[29];
  const float* ylab = (const float*)d_in[30];

  // workspace layout (_Float16 planes first, then ints/floats; all 16B-aligned)
  _Float16* H = (_Float16*)d_ws;                 // XELEMS
  _Float16* L = H + XELEMS;                      // XELEMS
  _Float16* meanH = L + XELEMS;                  // SELEMS
  _Float16* meanL = meanH + SELEMS;              // SELEMS
  _Float16* YH = meanL + SELEMS;                 // SELEMS
  _Float16* Wt = YH + SELEMS;                    // WT_ELEMS
  int* prefix = (int*)(Wt + WT_ELEMS);           // 546,004
  int* counts = prefix + 546004;                 // 546,000 (cursor)
  int* esrc = counts + NCOUNTS;                  // 2,300,000
  int* partials = esrc + NEDGES;                 // 1,024
  float* visitSumB = (float*)(partials + 1024);  // 512

  RelMeta rm;
  for (int r = 0; r < NREL; ++r) {
    rm.ei[r] = (const int*)d_in[12 + r];
    rm.E[r] = kEhA[r];
    rm.cbc[r] = kCbcA[r];
  }

  hipMemsetAsync(counts, 0, NCOUNTS * sizeof(int), stream);
  hipMemsetAsync(d_out, 0, sizeof(float), stream);

  prep_split<<<(1081856 + 255) / 256, 256, 0, stream>>>(W_l, b_l, W_r, cw1, Wt, visitSumB);

  GatherMeta gm;
  for (int t = 0; t < 6; ++t) {
    gm.nid[t] = (const int*)d_in[2 * t];
    gm.emb[t] = (const float*)d_in[2 * t + 1];
    gm.rows[t] = kRows[t];
    gm.off[t] = kOff[t];
  }
  conv0<<<dim3(6250, 6), 256, 0, stream>>>(gm, H, L);

  dim3 egrid(1172, NREL);
  hist_kernel<<<egrid, 256, 0, stream>>>(rm, counts);
  scan1<<<534, 1024, 0, stream>>>(counts, partials);
  scan2<<<1, 1024, 0, stream>>>(partials, 534);
  scan3<<<534, 1024, 0, stream>>>(counts, prefix, partials);
  scatter_kernel<<<egrid, 256, 0, stream>>>(rm, counts, esrc);

  _Float16* xvH = H + (size_t)kOff[1] * 128;
  _Float16* xvL = L + (size_t)kOff[1] * 128;

  for (int l = 0; l < 4; ++l) {
    int doRelu = (l < 3);
    int last = (l == 3);
    _Float16* LW = Wt + (size_t)l * PLW;

    // 1) small-dst means (h-gather of visit features); layer 3: drug only
    AggMeta am;
    if (!last) {
      for (int t = 0; t < 5; ++t) {
        am.rp[t] = prefix + kCbcIn[t];
        am.meanH[t] = meanH + (size_t)kYOff[t] * 128;
        am.meanL[t] = meanL + (size_t)kYOff[t] * 128;
        am.M[t] = kRows[kSmallT[t]];
      }
      agg_small<<<dim3(1250, 5), 256, 0, stream>>>(am, xvH, esrc);
    } else {
      am.rp[0] = prefix + kCbcIn[4];
      am.meanH[0] = meanH + (size_t)kYOff[4] * 128;
      am.meanL[0] = meanL + (size_t)kYOff[4] * 128;
      am.M[0] = 4000;
      agg_small<<<dim3(250, 1), 256, 0, stream>>>(am, xvH, esrc);
    }

    // 2) m2: Y_q = x_src @ Wl_q (h-only out) ; x_v = x_v @ SumWr + Sumb (split, in-place)
    MMeta m2;
    m2.nTasks = 6;
    for (int q = 0; q < 5; ++q) {
      size_t so = (size_t)kOff[kSmallT[q]] * 128;
      m2.t[q].AH0 = H + so; m2.t[q].AL0 = L + so;
      m2.t[q].AH1 = nullptr; m2.t[q].AL1 = nullptr;
      m2.t[q].W = LW + 337920 + (size_t)q * 34816;
      m2.t[q].bias = nullptr;
      m2.t[q].outH = YH + (size_t)kYOff[q] * 128;
      m2.t[q].outL = nullptr;
      m2.t[q].M = kRows[kSmallT[q]];
      m2.t[q].blkOff = kBOff[q];
      m2.t[q].K = 128;
      m2.t[q].relu = 0;
    }
    m2.t[5].AH0 = xvH; m2.t[5].AL0 = xvL;
    m2.t[5].AH1 = nullptr; m2.t[5].AL1 = nullptr;
    m2.t[5].W = LW + 512000;
    m2.t[5].bias = visitSumB + l * 128;
    m2.t[5].outH = xvH; m2.t[5].outL = xvL;   // in-place (block-local rows)
    m2.t[5].M = NVISIT;
    m2.t[5].blkOff = 363;
    m2.t[5].K = 128;
    m2.t[5].relu = 0;
    mgemm<<<dim3(363 + 782), 256, 0, stream>>>(m2);

    // 3) m1: small-dst [mean | x_old] @ [Wl;Wr] + b, split out, in-place
    MMeta m1;
    if (!last) {
      m1.nTasks = 5;
      for (int t = 0; t < 5; ++t) {
        size_t mo = (size_t)kYOff[t] * 128;
        size_t so = (size_t)kOff[kSmallT[t]] * 128;
        m1.t[t].AH0 = meanH + mo; m1.t[t].AL0 = meanL + mo;
        m1.t[t].AH1 = H + so;     m1.t[t].AL1 = L + so;
        m1.t[t].W = LW + (size_t)t * 67584;
        m1.t[t].bias = b_l + (size_t)(l * 10 + kInRel[t]) * 128;
        m1.t[t].outH = H + so;    m1.t[t].outL = L + so;
        m1.t[t].M = kRows[kSmallT[t]];
        m1.t[t].blkOff = kBOff[t];
        m1.t[t].K = 256;
        m1.t[t].relu = doRelu;
      }
      mgemm<<<dim3(363), 256, 0, stream>>>(m1);
    } else {
      size_t mo = (size_t)kYOff[4] * 128;
      size_t so = (size_t)kOff[5] * 128;   // drug
      m1.nTasks = 1;
      m1.t[0].AH0 = meanH + mo; m1.t[0].AL0 = meanL + mo;
      m1.t[0].AH1 = H + so;     m1.t[0].AL1 = L + so;
      m1.t[0].W = LW + (size_t)4 * 67584;
      m1.t[0].bias = b_l + (size_t)(l * 10 + kInRel[4]) * 128;
      m1.t[0].outH = H + so;    m1.t[0].outL = L + so;
      m1.t[0].M = 4000;
      m1.t[0].blkOff = 0;
      m1.t[0].K = 256;
      m1.t[0].relu = 0;
      mgemm<<<dim3(32), 256, 0, stream>>>(m1);
    }

    // 4) x_v(H,L) += sum_r mean_r(YH_r); relu; re-split
    VAggMeta va;
    for (int q = 0; q < 5; ++q) {
      va.rp[q] = prefix + kCbcVisit[q];
      va.Y[q] = YH + (size_t)kYOff[q] * 128;
    }
    agg_visit<<<dim3(6250), 256, 0, stream>>>(va, esrc, xvH, xvL, doRelu);
  }

  const int ML = 200000;
  mgemm_cls<<<dim3((ML + 127) / 128), 256, 0, stream>>>(
      xvH, H + (size_t)kOff[5] * 128, eli, Wt + (size_t)4 * PLW, cb1, cw2, cb2, ylab,
      (float*)d_out, (float*)d_out + 1, ML);
}

// Round 9
// 982.948 us; speedup vs baseline: 1.3293x; 1.1766x over previous
//
#include <hip/hip_runtime.h>
#include <cmath>

// ---------------------------------------------------------------------------
// Hetero-SAGE GNN (4 layers, 10 relations, D=128) + edge classifier.
// R9: CSR build replaced by block-aggregated bucket sort:
//   p1: per-block LDS counting (ranks via LDS atomics), ONE global atomic per
//       (block,bucket) run reservation, packed run writes (full lines).
//       Fixes R5's per-edge-atomic serialization AND R6/R8 scatter's 13x
//       partial-line write amplification. 873 buckets, cap 5120, dpb<=2048.
//   p2a: per-bucket LDS hist -> coalesced counts writes (hist_kernel deleted)
//   scan: unchanged. p2b: per-bucket LDS counting sort -> coalesced esrc runs.
// Carried from R8: split-f16 H/L planes, f16x3 MFMA GEMMs, h-only Y/gathers,
// in-place updates, layer-3 pruning.
// ---------------------------------------------------------------------------

typedef _Float16 f16x8 __attribute__((ext_vector_type(8)));
typedef _Float16 f16x4 __attribute__((ext_vector_type(4)));
typedef float f32x4 __attribute__((ext_vector_type(4)));

#define NREL 10
#define NCOUNTS 546000
#define NEDGES  2300000
#define NVISIT  100000
#define PLW 546816
#define WT_ELEMS (4 * PLW + 67584)
#define XELEMS 18688000UL   // 146000*128
#define SELEMS 5888000UL    // 46000*128
#define NBKT 873
#define BCAP 5120

struct GatherMeta { const float* emb[6]; const int* nid[6]; int rows[6]; int off[6]; };
struct AggMeta { const int* rp[5]; _Float16* meanH[5]; _Float16* meanL[5]; int M[5]; };
struct VAggMeta { const int* rp[5]; const _Float16* Y[5]; };
struct BkMeta {
  const int* ei[NREL]; int E[NREL]; int cbc[NREL]; int ndst[NREL];
  int sh[NREL]; int bb[NREL]; int nb[NREL];
};
struct MTask {
  const _Float16* AH0; const _Float16* AL0;  // k in [0,128)
  const _Float16* AH1; const _Float16* AL1;  // k in [128,256)
  const _Float16* W;                         // [2][128][Kpad] h then l plane
  const float* bias;                         // nullable
  _Float16* outH; _Float16* outL;            // outL nullable (h-only output)
  int M, blkOff, K, relu;
};
struct MMeta { MTask t[6]; int nTasks; };

// ---------------- conv0: emb -> split H/L planes ---------------------------
__global__ __launch_bounds__(256) void conv0(GatherMeta g, _Float16* __restrict__ H,
                                             _Float16* __restrict__ L) {
  int t = blockIdx.y;
  int i = blockIdx.x * 256 + threadIdx.x;
  if (i >= g.rows[t] * 16) return;
  int row = i >> 4, q = i & 15;
  int s = g.nid[t][row];
  const float* p = g.emb[t] + (size_t)s * 128 + q * 8;
  float4 v0 = *(const float4*)p;
  float4 v1 = *(const float4*)(p + 4);
  float v[8] = {v0.x, v0.y, v0.z, v0.w, v1.x, v1.y, v1.z, v1.w};
  f16x8 h, l;
  #pragma unroll
  for (int j = 0; j < 8; ++j) {
    h[j] = (_Float16)v[j];
    l[j] = (_Float16)(v[j] - (float)h[j]);
  }
  size_t o = (size_t)(g.off[t] + row) * 128 + q * 8;
  *(f16x8*)(H + o) = h;
  *(f16x8*)(L + o) = l;
}

// ---------------- CSR build: block-aggregated bucket sort ------------------
// p1: 4096 edges/block; LDS per-bucket count+rank; one global atomic per
// (block,bucket); packed run writes (dstLow<<17 | src).
__global__ __launch_bounds__(256) void bkt_p1(BkMeta bm, int* __restrict__ bcur,
                                              int* __restrict__ bdata) {
  __shared__ int cnt[128];
  __shared__ int base[128];
  __shared__ unsigned short rnk[4096];
  int r = blockIdx.y;
  int E = bm.E[r], sh = bm.sh[r], bb = bm.bb[r], nb = bm.nb[r];
  int tid = threadIdx.x;
  if (tid < 128) cnt[tid] = 0;
  __syncthreads();
  int e0 = blockIdx.x * 4096;
  if (e0 >= E) return;
  const int* dstp = bm.ei[r] + E;
  const int* srcp = bm.ei[r];
  #pragma unroll
  for (int i = 0; i < 16; ++i) {
    int e = e0 + i * 256 + tid;
    if (e < E) {
      int b = dstp[e] >> sh;
      rnk[i * 256 + tid] = (unsigned short)atomicAdd(&cnt[b], 1);
    }
  }
  __syncthreads();
  if (tid < nb && cnt[tid] > 0) base[tid] = atomicAdd(&bcur[bb + tid], cnt[tid]);
  __syncthreads();
  #pragma unroll
  for (int i = 0; i < 16; ++i) {
    int e = e0 + i * 256 + tid;
    if (e < E) {
      int d = dstp[e];
      int b = d >> sh;
      int pos = base[b] + (int)rnk[i * 256 + tid];
      if (pos < BCAP)
        bdata[(size_t)(bb + b) * BCAP + pos] = ((d & ((1 << sh) - 1)) << 17) | srcp[e];
    }
  }
}

// p2a: per-bucket LDS hist -> coalesced counts (replaces global hist atomics)
__global__ __launch_bounds__(256) void bkt_p2a(BkMeta bm, const int* __restrict__ bcur,
                                               const int* __restrict__ bdata,
                                               int* __restrict__ counts) {
  __shared__ int hist[2048];
  int g = blockIdx.x;
  int r = 0;
  #pragma unroll
  for (int i = 1; i < NREL; ++i) if (g >= bm.bb[i]) r = i;
  int lb = g - bm.bb[r];
  int sh = bm.sh[r], dpb = 1 << sh;
  int tid = threadIdx.x;
  for (int d = tid; d < dpb; d += 256) hist[d] = 0;
  __syncthreads();
  int cnt = bcur[g]; if (cnt > BCAP) cnt = BCAP;
  const int* bd = bdata + (size_t)g * BCAP;
  for (int i = tid; i < cnt; i += 256) atomicAdd(&hist[((unsigned)bd[i]) >> 17], 1);
  __syncthreads();
  int dBase = lb << sh;
  int dMax = bm.ndst[r] - dBase; if (dMax > dpb) dMax = dpb;
  for (int d = tid; d < dMax; d += 256) counts[bm.cbc[r] + dBase + d] = hist[d];
}

// ---------------- global scan (3-phase) ------------------------------------
__global__ __launch_bounds__(1024) void scan1(const int* __restrict__ counts,
                                              int* __restrict__ partials) {
  __shared__ int s[1024];
  int i = blockIdx.x * 1024 + threadIdx.x;
  s[threadIdx.x] = (i < NCOUNTS) ? counts[i] : 0;
  __syncthreads();
  for (int off = 512; off > 0; off >>= 1) {
    if (threadIdx.x < off) s[threadIdx.x] += s[threadIdx.x + off];
    __syncthreads();
  }
  if (threadIdx.x == 0) partials[blockIdx.x] = s[0];
}

__global__ __launch_bounds__(1024) void scan2(int* __restrict__ partials, int nb) {
  __shared__ int s[1024];
  int t = threadIdx.x;
  int v = (t < nb) ? partials[t] : 0;
  s[t] = v;
  __syncthreads();
  for (int off = 1; off < 1024; off <<= 1) {
    int add = (t >= off) ? s[t - off] : 0;
    __syncthreads();
    s[t] += add;
    __syncthreads();
  }
  if (t < nb) partials[t] = s[t] - v;  // exclusive
}

__global__ __launch_bounds__(1024) void scan3(const int* __restrict__ counts,
                                              int* __restrict__ prefix,
                                              const int* __restrict__ partials) {
  __shared__ int s[1024];
  int t = threadIdx.x;
  int i = blockIdx.x * 1024 + t;
  int v = (i < NCOUNTS) ? counts[i] : 0;
  s[t] = v;
  __syncthreads();
  for (int off = 1; off < 1024; off <<= 1) {
    int add = (t >= off) ? s[t - off] : 0;
    __syncthreads();
    s[t] += add;
    __syncthreads();
  }
  int P = partials[blockIdx.x] + s[t] - v;
  if (i < NCOUNTS) prefix[i] = P;
  if (blockIdx.x == 0 && t == 0) prefix[NCOUNTS] = NEDGES;
}

// p2b: per-bucket LDS counting sort -> contiguous coalesced esrc run
__global__ __launch_bounds__(256) void bkt_p2b(BkMeta bm, const int* __restrict__ bcur,
                                               const int* __restrict__ bdata,
                                               const int* __restrict__ prefix,
                                               int* __restrict__ esrc) {
  __shared__ int pk[BCAP];
  __shared__ int srt[BCAP];
  __shared__ int cur[2048];
  __shared__ int part[256];
  __shared__ int baseSh;
  int g = blockIdx.x;
  int r = 0;
  #pragma unroll
  for (int i = 1; i < NREL; ++i) if (g >= bm.bb[i]) r = i;
  int lb = g - bm.bb[r];
  int sh = bm.sh[r], dpb = 1 << sh;
  int tid = threadIdx.x;
  int cnt = bcur[g]; if (cnt > BCAP) cnt = BCAP;
  const int* bd = bdata + (size_t)g * BCAP;
  for (int d = tid; d < dpb; d += 256) cur[d] = 0;
  for (int i = tid; i < cnt; i += 256) pk[i] = bd[i];
  __syncthreads();
  for (int i = tid; i < cnt; i += 256) atomicAdd(&cur[((unsigned)pk[i]) >> 17], 1);
  __syncthreads();
  int seg = (dpb + 255) >> 8;
  int s = 0;
  int b0 = tid * seg;
  for (int j = 0; j < seg; ++j) {
    int idx = b0 + j;
    if (idx < dpb) { int v = cur[idx]; cur[idx] = s; s += v; }
  }
  part[tid] = s;
  __syncthreads();
  for (int off = 1; off < 256; off <<= 1) {
    int add = (tid >= off) ? part[tid - off] : 0;
    __syncthreads();
    part[tid] += add;
    __syncthreads();
  }
  int myoff = part[tid] - s;
  for (int j = 0; j < seg; ++j) {
    int idx = b0 + j;
    if (idx < dpb) cur[idx] += myoff;
  }
  if (tid == 0) baseSh = prefix[bm.cbc[r] + (lb << sh)];
  __syncthreads();
  for (int i = tid; i < cnt; i += 256) {
    int p = pk[i];
    int pos = atomicAdd(&cur[((unsigned)p) >> 17], 1);
    srt[pos] = p & 0x1FFFF;
  }
  __syncthreads();
  int base = baseSh;
  for (int i = tid; i < cnt; i += 256) esrc[base + i] = srt[i];
}

// ---------------- weight split/transpose prep ------------------------------
__global__ __launch_bounds__(256) void prep_split(
    const float* __restrict__ W_l, const float* __restrict__ b_l,
    const float* __restrict__ W_r, const float* __restrict__ cw1,
    _Float16* __restrict__ Wt, float* __restrict__ visitSumB) {
  const int visitRel[5] = {0, 3, 5, 7, 9};
  const int inRel[5] = {1, 2, 4, 6, 8};
  int gid = blockIdx.x * 256 + threadIdx.x;
  if (gid < 1048576) {
    int l = gid >> 18, o = gid & 262143;
    float val; size_t base; int n, k, Kpad;
    if (o < 163840) {          // small stacks, K=256
      int t = o >> 15, e = o & 32767;
      k = e >> 7; n = e & 127; Kpad = 264;
      int r = inRel[t];
      val = (k < 128) ? W_l[(size_t)(l * 10 + r) * 16384 + k * 128 + n]
                      : W_r[(size_t)(l * 10 + r) * 16384 + (k - 128) * 128 + n];
      base = (size_t)l * PLW + t * 67584;
    } else if (o < 245760) {   // trans Wl, K=128
      int q = (o - 163840) >> 14, e = (o - 163840) & 16383;
      k = e >> 7; n = e & 127; Kpad = 136;
      val = W_l[(size_t)(l * 10 + visitRel[q]) * 16384 + k * 128 + n];
      base = (size_t)l * PLW + 337920 + q * 34816;
    } else {                   // SumWr, K=128
      int e = o - 245760;
      k = e >> 7; n = e & 127; Kpad = 136;
      val = 0.f;
      #pragma unroll
      for (int q = 0; q < 5; ++q)
        val += W_r[(size_t)(l * 10 + visitRel[q]) * 16384 + k * 128 + n];
      base = (size_t)l * PLW + 512000;
    }
    _Float16 h = (_Float16)val;
    _Float16 lo = (_Float16)(val - (float)h);
    Wt[base + (size_t)n * Kpad + k] = h;
    Wt[base + (size_t)(128 + n) * Kpad + k] = lo;
  } else if (gid < 1081344) {  // cls W1, K=256
    int e = gid - 1048576;
    int k = e >> 7, n = e & 127;
    float val = cw1[(size_t)k * 128 + n];
    _Float16 h = (_Float16)val;
    _Float16 lo = (_Float16)(val - (float)h);
    size_t base = (size_t)4 * PLW;
    Wt[base + (size_t)n * 264 + k] = h;
    Wt[base + (size_t)(128 + n) * 264 + k] = lo;
  } else if (gid < 1081856) {  // visit summed bias
    int e = gid - 1081344;
    int l = e >> 7, c = e & 127;
    float val = 0.f;
    #pragma unroll
    for (int q = 0; q < 5; ++q) val += b_l[(l * 10 + visitRel[q]) * 128 + c];
    visitSumB[e] = val;
  }
}

// ---------------- small-dst means: gather H(visit), write split means ------
__global__ __launch_bounds__(256) void agg_small(AggMeta m,
                                                 const _Float16* __restrict__ xvH,
                                                 const int* __restrict__ esrc) {
  int t = blockIdx.y;
  int row = blockIdx.x * 16 + (threadIdx.x >> 4);
  if (row >= m.M[t]) return;
  int q = threadIdx.x & 15;
  const int* rp = m.rp[t];
  int e0 = rp[row], e1 = rp[row + 1];
  float a[8];
  #pragma unroll
  for (int j = 0; j < 8; ++j) a[j] = 0.f;
  int e = e0;
  for (; e + 4 <= e1; e += 4) {
    int s0 = esrc[e], s1 = esrc[e + 1], s2 = esrc[e + 2], s3 = esrc[e + 3];
    f16x8 v0 = *(const f16x8*)(xvH + (size_t)s0 * 128 + q * 8);
    f16x8 v1 = *(const f16x8*)(xvH + (size_t)s1 * 128 + q * 8);
    f16x8 v2 = *(const f16x8*)(xvH + (size_t)s2 * 128 + q * 8);
    f16x8 v3 = *(const f16x8*)(xvH + (size_t)s3 * 128 + q * 8);
    #pragma unroll
    for (int j = 0; j < 8; ++j)
      a[j] += ((float)v0[j] + (float)v1[j]) + ((float)v2[j] + (float)v3[j]);
  }
  for (; e < e1; ++e) {
    int s = esrc[e];
    f16x8 v = *(const f16x8*)(xvH + (size_t)s * 128 + q * 8);
    #pragma unroll
    for (int j = 0; j < 8; ++j) a[j] += (float)v[j];
  }
  float inv = (e1 > e0) ? 1.f / (float)(e1 - e0) : 0.f;
  f16x8 h, l;
  #pragma unroll
  for (int j = 0; j < 8; ++j) {
    float v = a[j] * inv;
    h[j] = (_Float16)v;
    l[j] = (_Float16)(v - (float)h[j]);
  }
  size_t o = (size_t)row * 128 + q * 8;
  *(f16x8*)(m.meanH[t] + o) = h;
  *(f16x8*)(m.meanL[t] + o) = l;
}

// ---------------- visit agg: H/L += sum_r mean_r(YH_r); relu; split back ---
__global__ __launch_bounds__(256) void agg_visit(VAggMeta va, const int* __restrict__ esrc,
                                                 _Float16* __restrict__ xvH,
                                                 _Float16* __restrict__ xvL, int doRelu) {
  int row = blockIdx.x * 16 + (threadIdx.x >> 4);
  if (row >= NVISIT) return;
  int q = threadIdx.x & 15;
  size_t o = (size_t)row * 128 + q * 8;
  f16x8 h0 = *(f16x8*)(xvH + o);
  f16x8 l0 = *(f16x8*)(xvL + o);
  float a[8];
  #pragma unroll
  for (int j = 0; j < 8; ++j) a[j] = (float)h0[j] + (float)l0[j];
  #pragma unroll
  for (int r = 0; r < 5; ++r) {
    int e0 = va.rp[r][row], e1 = va.rp[r][row + 1];
    if (e1 > e0) {
      const _Float16* Y = va.Y[r];
      float s[8];
      #pragma unroll
      for (int j = 0; j < 8; ++j) s[j] = 0.f;
      int e = e0;
      for (; e + 4 <= e1; e += 4) {
        int s0 = esrc[e], s1 = esrc[e + 1], s2 = esrc[e + 2], s3 = esrc[e + 3];
        f16x8 v0 = *(const f16x8*)(Y + (size_t)s0 * 128 + q * 8);
        f16x8 v1 = *(const f16x8*)(Y + (size_t)s1 * 128 + q * 8);
        f16x8 v2 = *(const f16x8*)(Y + (size_t)s2 * 128 + q * 8);
        f16x8 v3 = *(const f16x8*)(Y + (size_t)s3 * 128 + q * 8);
        #pragma unroll
        for (int j = 0; j < 8; ++j)
          s[j] += ((float)v0[j] + (float)v1[j]) + ((float)v2[j] + (float)v3[j]);
      }
      for (; e < e1; ++e) {
        int si = esrc[e];
        f16x8 v = *(const f16x8*)(Y + (size_t)si * 128 + q * 8);
        #pragma unroll
        for (int j = 0; j < 8; ++j) s[j] += (float)v[j];
      }
      float inv = 1.f / (float)(e1 - e0);
      #pragma unroll
      for (int j = 0; j < 8; ++j) a[j] += s[j] * inv;
    }
  }
  f16x8 h, l;
  #pragma unroll
  for (int j = 0; j < 8; ++j) {
    float v = doRelu ? fmaxf(a[j], 0.f) : a[j];
    h[j] = (_Float16)v;
    l[j] = (_Float16)(v - (float)h[j]);
  }
  *(f16x8*)(xvH + o) = h;
  *(f16x8*)(xvL + o) = l;
}

// ---------------- MFMA f16x3 GEMM, multi-task, split-plane A ---------------
__global__ __launch_bounds__(256, 2) void mgemm(MMeta mm) {
  int b = blockIdx.x;
  int ti = 0;
  for (int i = 1; i < mm.nTasks; ++i) if (b >= mm.t[i].blkOff) ti = i;
  MTask tk = mm.t[ti];
  int blockRow = (b - tk.blkOff) * 128;
  int Kpad = tk.K + 8;

  __shared__ _Float16 Ash[2][128][72];
  int tid = threadIdx.x;
  int wave = tid >> 6, lane = tid & 63;
  int quad = lane >> 4, lm = lane & 15;
  int wr = wave >> 1, wc = wave & 1;

  f32x4 acc[4][4];
  #pragma unroll
  for (int i = 0; i < 4; ++i)
    #pragma unroll
    for (int j = 0; j < 4; ++j) acc[i][j] = (f32x4){0.f, 0.f, 0.f, 0.f};

  const _Float16* wrowH[4];
  const _Float16* wrowL[4];
  #pragma unroll
  for (int nt = 0; nt < 4; ++nt) {
    int n = wc * 64 + nt * 16 + lm;
    wrowH[nt] = tk.W + (size_t)n * Kpad;
    wrowL[nt] = tk.W + (size_t)(128 + n) * Kpad;
  }

  int sr = tid >> 1, sk = (tid & 1) * 32;
  int gr = blockRow + sr; if (gr >= tk.M) gr = tk.M - 1;  // clamp (dup row ok)
  for (int k0 = 0; k0 < tk.K; k0 += 64) {
    const _Float16* AH = (k0 < 128) ? tk.AH0 : tk.AH1;
    const _Float16* AL = (k0 < 128) ? tk.AL0 : tk.AL1;
    size_t abase = (size_t)gr * 128 + (k0 & 127) + sk;
    #pragma unroll
    for (int c = 0; c < 4; ++c) {
      *(f16x8*)&Ash[0][sr][sk + c * 8] = *(const f16x8*)(AH + abase + c * 8);
      *(f16x8*)&Ash[1][sr][sk + c * 8] = *(const f16x8*)(AL + abase + c * 8);
    }
    __syncthreads();
    #pragma unroll
    for (int ks = 0; ks < 64; ks += 32) {
      int kf = k0 + ks + quad * 8;
      f16x8 bh[4], bl[4];
      #pragma unroll
      for (int nt = 0; nt < 4; ++nt) {
        bh[nt] = *(const f16x8*)(wrowH[nt] + kf);
        bl[nt] = *(const f16x8*)(wrowL[nt] + kf);
      }
      #pragma unroll
      for (int mt = 0; mt < 4; ++mt) {
        int r = wr * 64 + mt * 16 + lm;
        f16x8 ah = *(const f16x8*)&Ash[0][r][ks + quad * 8];
        f16x8 al = *(const f16x8*)&Ash[1][r][ks + quad * 8];
        #pragma unroll
        for (int nt = 0; nt < 4; ++nt) {
          acc[mt][nt] = __builtin_amdgcn_mfma_f32_16x16x32_f16(ah, bh[nt], acc[mt][nt], 0, 0, 0);
          acc[mt][nt] = __builtin_amdgcn_mfma_f32_16x16x32_f16(ah, bl[nt], acc[mt][nt], 0, 0, 0);
          acc[mt][nt] = __builtin_amdgcn_mfma_f32_16x16x32_f16(al, bh[nt], acc[mt][nt], 0, 0, 0);
        }
      }
    }
    __syncthreads();
  }

  float bv[4];
  #pragma unroll
  for (int nt = 0; nt < 4; ++nt)
    bv[nt] = tk.bias ? tk.bias[wc * 64 + nt * 16 + lm] : 0.f;
  #pragma unroll
  for (int mt = 0; mt < 4; ++mt) {
    #pragma unroll
    for (int i = 0; i < 4; ++i) {
      int grow = blockRow + wr * 64 + mt * 16 + quad * 4 + i;
      if (grow >= tk.M) continue;
      size_t ob = (size_t)grow * 128 + wc * 64 + lm;
      #pragma unroll
      for (int nt = 0; nt < 4; ++nt) {
        float v = acc[mt][nt][i] + bv[nt];
        if (tk.relu) v = fmaxf(v, 0.f);
        _Float16 h = (_Float16)v;
        tk.outH[ob + nt * 16] = h;
        if (tk.outL) tk.outL[ob + nt * 16] = (_Float16)(v - (float)h);
      }
    }
  }
}

// ---------------- MFMA classifier (H-plane gathers, f16x2 B) ---------------
__global__ __launch_bounds__(256, 2) void mgemm_cls(
    const _Float16* __restrict__ xv16, const _Float16* __restrict__ xd16,
    const int* __restrict__ eli, const _Float16* __restrict__ W,  // [2][128][264]
    const float* __restrict__ b1, const float* __restrict__ w2,
    const float* __restrict__ b2, const float* __restrict__ y,
    float* __restrict__ lossOut, float* __restrict__ pred, int M) {
  __shared__ _Float16 Ash[128][72];
  __shared__ int idxA[128];
  __shared__ int idxB[128];
  __shared__ float predPart[128];
  __shared__ float redL[128];
  int tid = threadIdx.x;
  int wave = tid >> 6, lane = tid & 63;
  int quad = lane >> 4, lm = lane & 15;
  int wr = wave >> 1, wc = wave & 1;
  int blockRow = blockIdx.x * 128;
  if (tid < 128) {
    int gr = blockRow + tid;
    idxA[tid] = (gr < M) ? eli[gr] : 0;
  } else {
    int t2 = tid - 128;
    int gr = blockRow + t2;
    idxB[t2] = (gr < M) ? eli[M + gr] : 0;
  }
  f32x4 acc[4][4];
  #pragma unroll
  for (int i = 0; i < 4; ++i)
    #pragma unroll
    for (int j = 0; j < 4; ++j) acc[i][j] = (f32x4){0.f, 0.f, 0.f, 0.f};

  const _Float16* wrowH[4];
  const _Float16* wrowL[4];
  #pragma unroll
  for (int nt = 0; nt < 4; ++nt) {
    int n = wc * 64 + nt * 16 + lm;
    wrowH[nt] = W + (size_t)n * 264;
    wrowL[nt] = W + (size_t)(128 + n) * 264;
  }
  __syncthreads();

  int sr = tid >> 1, sk = (tid & 1) * 32;
  for (int k0 = 0; k0 < 256; k0 += 64) {
    const _Float16* base = (k0 < 128) ? xv16 : xd16;
    int srcRow = (k0 < 128) ? idxA[sr] : idxB[sr];
    const _Float16* p = base + (size_t)srcRow * 128 + (k0 & 127) + sk;
    #pragma unroll
    for (int c = 0; c < 4; ++c)
      *(f16x8*)&Ash[sr][sk + c * 8] = *(const f16x8*)(p + c * 8);
    __syncthreads();
    #pragma unroll
    for (int ks = 0; ks < 64; ks += 32) {
      int kf = k0 + ks + quad * 8;
      f16x8 bh[4], bl[4];
      #pragma unroll
      for (int nt = 0; nt < 4; ++nt) {
        bh[nt] = *(const f16x8*)(wrowH[nt] + kf);
        bl[nt] = *(const f16x8*)(wrowL[nt] + kf);
      }
      #pragma unroll
      for (int mt = 0; mt < 4; ++mt) {
        int r = wr * 64 + mt * 16 + lm;
        f16x8 ah = *(const f16x8*)&Ash[r][ks + quad * 8];
        #pragma unroll
        for (int nt = 0; nt < 4; ++nt) {
          acc[mt][nt] = __builtin_amdgcn_mfma_f32_16x16x32_f16(ah, bh[nt], acc[mt][nt], 0, 0, 0);
          acc[mt][nt] = __builtin_amdgcn_mfma_f32_16x16x32_f16(ah, bl[nt], acc[mt][nt], 0, 0, 0);
        }
      }
    }
    __syncthreads();
  }

  float b1v[4], w2v[4];
  #pragma unroll
  for (int nt = 0; nt < 4; ++nt) {
    int col = wc * 64 + nt * 16 + lm;
    b1v[nt] = b1[col];
    w2v[nt] = w2[col];
  }
  float rowp[4][4];
  #pragma unroll
  for (int mt = 0; mt < 4; ++mt)
    #pragma unroll
    for (int i = 0; i < 4; ++i) {
      float p = 0.f;
      #pragma unroll
      for (int nt = 0; nt < 4; ++nt)
        p += fmaxf(acc[mt][nt][i] + b1v[nt], 0.f) * w2v[nt];
      p += __shfl_xor(p, 1);
      p += __shfl_xor(p, 2);
      p += __shfl_xor(p, 4);
      p += __shfl_xor(p, 8);
      rowp[mt][i] = p;
    }
  if (wc == 0 && lm == 0) {
    #pragma unroll
    for (int mt = 0; mt < 4; ++mt)
      #pragma unroll
      for (int i = 0; i < 4; ++i)
        predPart[wr * 64 + mt * 16 + quad * 4 + i] = rowp[mt][i];
  }
  __syncthreads();
  if (wc == 1 && lm == 0) {
    #pragma unroll
    for (int mt = 0; mt < 4; ++mt)
      #pragma unroll
      for (int i = 0; i < 4; ++i)
        predPart[wr * 64 + mt * 16 + quad * 4 + i] += rowp[mt][i];
  }
  __syncthreads();
  if (tid < 128) {
    int gr = blockRow + tid;
    float lv = 0.f;
    if (gr < M) {
      float z = predPart[tid] + b2[0];
      pred[gr] = z;
      lv = fmaxf(z, 0.f) + log1pf(expf(-fabsf(z))) - z * y[gr];
    }
    redL[tid] = lv;
  }
  __syncthreads();
  if (tid == 0) {
    float s = 0.f;
    for (int i = 0; i < 128; ++i) s += redL[i];
    atomicAdd(lossOut, s * (1.0f / 200000.0f));
  }
}

// ---------------------------------------------------------------------------
extern "C" void kernel_launch(void* const* d_in, const int* in_sizes, int n_in,
                              void* d_out, int out_size, void* d_ws, size_t ws_size,
                              hipStream_t stream) {
  static const int kRows[6] = {20000, 100000, 4000, 8000, 10000, 4000};
  static const int kOff[6]  = {0, 20000, 120000, 124000, 132000, 142000};
  static const int kSmallT[5]   = {0, 2, 3, 4, 5};
  static const int kInRel[5]    = {1, 2, 4, 6, 8};
  static const int kCbcIn[5]    = {100000, 120000, 224000, 332000, 442000};
  static const int kCbcVisit[5] = {0, 124000, 232000, 342000, 446000};
  static const int kYOff[5]     = {0, 20000, 24000, 32000, 42000};
  static const int kBOff[5]     = {0, 157, 189, 252, 331};
  // bucket config (rel order: pv,vp,vs,sv,vpr,prv,vd,dv,vdr,drv)
  static const int kCbcA[NREL]  = {0, 100000, 120000, 124000, 224000,
                                   232000, 332000, 342000, 442000, 446000};
  static const int kEhA[NREL]   = {100000, 100000, 300000, 300000, 200000,
                                   200000, 250000, 250000, 300000, 300000};
  static const int kNdst[NREL]  = {100000, 20000, 4000, 100000, 8000,
                                   100000, 10000, 100000, 4000, 100000};
  static const int kSh[NREL]    = {11, 9, 5, 10, 7, 10, 7, 10, 5, 10};
  static const int kNB[NREL]    = {49, 40, 125, 98, 63, 98, 79, 98, 125, 98};
  static const int kBB[NREL]    = {0, 49, 89, 214, 312, 375, 473, 552, 650, 775};

  const float* W_l = (const float*)d_in[22];
  const float* b_l = (const float*)d_in[23];
  const float* W_r = (const float*)d_in[24];
  const float* cw1 = (const float*)d_in[25];
  const float* cb1 = (const float*)d_in[26];
  const float* cw2 = (const float*)d_in[27];
  const float* cb2 = (const float*)d_in[28];
  const int* eli = (const int*)d_in[29];
  const float* ylab = (const float*)d_in[30];

  // workspace layout
  _Float16* H = (_Float16*)d_ws;                 // XELEMS
  _Float16* L = H + XELEMS;                      // XELEMS
  _Float16* meanH = L + XELEMS;                  // SELEMS
  _Float16* meanL = meanH + SELEMS;              // SELEMS
  _Float16* YH = meanL + SELEMS;                 // SELEMS
  _Float16* Wt = YH + SELEMS;                    // WT_ELEMS
  int* prefix = (int*)(Wt + WT_ELEMS);           // 546,004
  int* counts = prefix + 546004;                 // 546,000
  int* esrc = counts + NCOUNTS;                  // 2,300,000
  int* partials = esrc + NEDGES;                 // 1,024
  float* visitSumB = (float*)(partials + 1024);  // 512
  int* bcur = (int*)(visitSumB + 512);           // NBKT (+pad)
  int* bdata = bcur + 1024;                      // NBKT * BCAP ints

  BkMeta bm;
  for (int r = 0; r < NREL; ++r) {
    bm.ei[r] = (const int*)d_in[12 + r];
    bm.E[r] = kEhA[r];
    bm.cbc[r] = kCbcA[r];
    bm.ndst[r] = kNdst[r];
    bm.sh[r] = kSh[r];
    bm.bb[r] = kBB[r];
    bm.nb[r] = kNB[r];
  }

  hipMemsetAsync(bcur, 0, NBKT * sizeof(int), stream);
  hipMemsetAsync(d_out, 0, sizeof(float), stream);

  prep_split<<<(1081856 + 255) / 256, 256, 0, stream>>>(W_l, b_l, W_r, cw1, Wt, visitSumB);

  GatherMeta gm;
  for (int t = 0; t < 6; ++t) {
    gm.nid[t] = (const int*)d_in[2 * t];
    gm.emb[t] = (const float*)d_in[2 * t + 1];
    gm.rows[t] = kRows[t];
    gm.off[t] = kOff[t];
  }
  conv0<<<dim3(6250, 6), 256, 0, stream>>>(gm, H, L);

  // CSR build: bucket append -> per-bucket hist -> scan -> per-bucket sort
  bkt_p1<<<dim3(74, NREL), 256, 0, stream>>>(bm, bcur, bdata);
  bkt_p2a<<<dim3(NBKT), 256, 0, stream>>>(bm, bcur, bdata, counts);
  scan1<<<534, 1024, 0, stream>>>(counts, partials);
  scan2<<<1, 1024, 0, stream>>>(partials, 534);
  scan3<<<534, 1024, 0, stream>>>(counts, prefix, partials);
  bkt_p2b<<<dim3(NBKT), 256, 0, stream>>>(bm, bcur, bdata, prefix, esrc);

  _Float16* xvH = H + (size_t)kOff[1] * 128;
  _Float16* xvL = L + (size_t)kOff[1] * 128;

  for (int l = 0; l < 4; ++l) {
    int doRelu = (l < 3);
    int last = (l == 3);
    _Float16* LW = Wt + (size_t)l * PLW;

    // 1) small-dst means (h-gather of visit features); layer 3: drug only
    AggMeta am;
    if (!last) {
      for (int t = 0; t < 5; ++t) {
        am.rp[t] = prefix + kCbcIn[t];
        am.meanH[t] = meanH + (size_t)kYOff[t] * 128;
        am.meanL[t] = meanL + (size_t)kYOff[t] * 128;
        am.M[t] = kRows[kSmallT[t]];
      }
      agg_small<<<dim3(1250, 5), 256, 0, stream>>>(am, xvH, esrc);
    } else {
      am.rp[0] = prefix + kCbcIn[4];
      am.meanH[0] = meanH + (size_t)kYOff[4] * 128;
      am.meanL[0] = meanL + (size_t)kYOff[4] * 128;
      am.M[0] = 4000;
      agg_small<<<dim3(250, 1), 256, 0, stream>>>(am, xvH, esrc);
    }

    // 2) m2: Y_q = x_src @ Wl_q (h-only out) ; x_v = x_v @ SumWr + Sumb (split, in-place)
    MMeta m2;
    m2.nTasks = 6;
    for (int q = 0; q < 5; ++q) {
      size_t so = (size_t)kOff[kSmallT[q]] * 128;
      m2.t[q].AH0 = H + so; m2.t[q].AL0 = L + so;
      m2.t[q].AH1 = nullptr; m2.t[q].AL1 = nullptr;
      m2.t[q].W = LW + 337920 + (size_t)q * 34816;
      m2.t[q].bias = nullptr;
      m2.t[q].outH = YH + (size_t)kYOff[q] * 128;
      m2.t[q].outL = nullptr;
      m2.t[q].M = kRows[kSmallT[q]];
      m2.t[q].blkOff = kBOff[q];
      m2.t[q].K = 128;
      m2.t[q].relu = 0;
    }
    m2.t[5].AH0 = xvH; m2.t[5].AL0 = xvL;
    m2.t[5].AH1 = nullptr; m2.t[5].AL1 = nullptr;
    m2.t[5].W = LW + 512000;
    m2.t[5].bias = visitSumB + l * 128;
    m2.t[5].outH = xvH; m2.t[5].outL = xvL;   // in-place (block-local rows)
    m2.t[5].M = NVISIT;
    m2.t[5].blkOff = 363;
    m2.t[5].K = 128;
    m2.t[5].relu = 0;
    mgemm<<<dim3(363 + 782), 256, 0, stream>>>(m2);

    // 3) m1: small-dst [mean | x_old] @ [Wl;Wr] + b, split out, in-place
    MMeta m1;
    if (!last) {
      m1.nTasks = 5;
      for (int t = 0; t < 5; ++t) {
        size_t mo = (size_t)kYOff[t] * 128;
        size_t so = (size_t)kOff[kSmallT[t]] * 128;
        m1.t[t].AH0 = meanH + mo; m1.t[t].AL0 = meanL + mo;
        m1.t[t].AH1 = H + so;     m1.t[t].AL1 = L + so;
        m1.t[t].W = LW + (size_t)t * 67584;
        m1.t[t].bias = b_l + (size_t)(l * 10 + kInRel[t]) * 128;
        m1.t[t].outH = H + so;    m1.t[t].outL = L + so;
        m1.t[t].M = kRows[kSmallT[t]];
        m1.t[t].blkOff = kBOff[t];
        m1.t[t].K = 256;
        m1.t[t].relu = doRelu;
      }
      mgemm<<<dim3(363), 256, 0, stream>>>(m1);
    } else {
      size_t mo = (size_t)kYOff[4] * 128;
      size_t so = (size_t)kOff[5] * 128;   // drug
      m1.nTasks = 1;
      m1.t[0].AH0 = meanH + mo; m1.t[0].AL0 = meanL + mo;
      m1.t[0].AH1 = H + so;     m1.t[0].AL1 = L + so;
      m1.t[0].W = LW + (size_t)4 * 67584;
      m1.t[0].bias = b_l + (size_t)(l * 10 + kInRel[4]) * 128;
      m1.t[0].outH = H + so;    m1.t[0].outL = L + so;
      m1.t[0].M = 4000;
      m1.t[0].blkOff = 0;
      m1.t[0].K = 256;
      m1.t[0].relu = 0;
      mgemm<<<dim3(32), 256, 0, stream>>>(m1);
    }

    // 4) x_v(H,L) += sum_r mean_r(YH_r); relu; re-split
    VAggMeta va;
    for (int q = 0; q < 5; ++q) {
      va.rp[q] = prefix + kCbcVisit[q];
      va.Y[q] = YH + (size_t)kYOff[q] * 128;
    }
    agg_visit<<<dim3(6250), 256, 0, stream>>>(va, esrc, xvH, xvL, doRelu);
  }

  const int ML = 200000;
  mgemm_cls<<<dim3((ML + 127) / 128), 256, 0, stream>>>(
      xvH, H + (size_t)kOff[5] * 128, eli, Wt + (size_t)4 * PLW, cb1, cw2, cb2, ylab,
      (float*)d_out, (float*)d_out + 1, ML);
}